// Round 10
// baseline (753.046 us; speedup 1.0000x reference)
//
#include <hip/hip_runtime.h>
#include <hip/hip_bf16.h>
#include <cstddef>
#include <cstdint>

// Problem constants (match reference setup_inputs)
constexpr int NN    = 50000;   // nodes
constexpr int EE    = 500000;  // edges
constexpr int FF    = 128;     // input feature dim
constexpr int HIDC  = 64;      // hidden per head
constexpr int NHEAD = 4;
constexpr int HC    = 256;     // NHEAD * HIDC
constexpr int GG    = 256;     // graphs

typedef __attribute__((ext_vector_type(2))) float f32x2;
typedef __attribute__((ext_vector_type(4))) float f32x4;
typedef __attribute__((ext_vector_type(8))) short bf16x8;

// CSR edge record: src byte-offset (src*1024) + the 6 edge features. 32 B.
struct __align__(16) EPack { int soff; int pad; float e0, e1, e2, e3, e4, e5; };

// round-to-nearest-even fp32 -> bf16 (as short)
__device__ inline short f2bf(float f) {
  union { float f; unsigned u; } v; v.f = f;
  unsigned r = v.u + 0x7fffu + ((v.u >> 16) & 1u);
  return (short)(r >> 16);
}

// unpack 4 bf16 (as uint2) -> two f32x2
__device__ inline void bf4_unpack(uint2 v, f32x2& a, f32x2& b) {
  union { unsigned u; float f; } t;
  t.u = v.x << 16;          a.x = t.f;
  t.u = v.x & 0xffff0000u;  a.y = t.f;
  t.u = v.y << 16;          b.x = t.f;
  t.u = v.y & 0xffff0000u;  b.y = t.f;
}

// ---------------------------------------------------------------------------
// Weight-conversion job table (all 6 matrices)
// ---------------------------------------------------------------------------
struct WtJobs {
  const float* w[6];
  short* o[6];
  int K[6], N[6];
  int cum[7];
};

// ---------------------------------------------------------------------------
// Prep kernel: zero deg + gp + pairs tail, convert x -> bf16, convert all
// weights (transpose+bf16). One dispatch replaces 5.
// ---------------------------------------------------------------------------
__global__ void prep_all(const float* __restrict__ x, short* __restrict__ xbf,
                         int* __restrict__ deg, float* __restrict__ gp,
                         int* __restrict__ pairs_tail, WtJobs j) {
  int i = blockIdx.x * blockDim.x + threadIdx.x;
  if (i < NN * FF) xbf[i] = f2bf(x[i]);
  if (i < NN) deg[i] = 0;
  if (i < GG * HIDC) gp[i] = 0.f;
  if (i < 16 * 8) pairs_tail[i] = 0;           // 16 EPack tail entries
  if (i < j.cum[6]) {
    int s = 0;
    while (i >= j.cum[s + 1]) s++;
    int li = i - j.cum[s];
    int K = j.K[s], N = j.N[s];
    int n = li / K, k = li - n * K;
    j.o[s][li] = f2bf(j.w[s][k * N + n]);
  }
}

// ---------------------------------------------------------------------------
// CSR build (by destination node)
// ---------------------------------------------------------------------------
__global__ void count_deg(const int* __restrict__ dst, int* __restrict__ deg) {
  int i = blockIdx.x * blockDim.x + threadIdx.x;
  if (i < EE) atomicAdd(&deg[dst[i]], 1);
}

__global__ __launch_bounds__(1024) void scan_offs(const int* __restrict__ deg,
                                                  int* __restrict__ offs,
                                                  int* __restrict__ cur) {
  __shared__ int sums[1024];
  int t = threadIdx.x;
  const int chunk = (NN + 1023) / 1024;
  int beg = t * chunk;
  int end = beg + chunk; if (end > NN) end = NN; if (beg > NN) beg = NN;
  int s = 0;
  for (int i = beg; i < end; i++) s += deg[i];
  sums[t] = s;
  __syncthreads();
  for (int off = 1; off < 1024; off <<= 1) {
    int v = (t >= off) ? sums[t - off] : 0;
    __syncthreads();
    sums[t] += v;
    __syncthreads();
  }
  int run = (t == 0) ? 0 : sums[t - 1];
  for (int i = beg; i < end; i++) {
    offs[i] = run; cur[i] = run; run += deg[i];
  }
  if (t == 1023) offs[NN] = run;
}

__global__ void fill_edges(const int* __restrict__ src, const int* __restrict__ dst,
                           const float* __restrict__ eattr,
                           int* __restrict__ cur, EPack* __restrict__ pairs) {
  int i = blockIdx.x * blockDim.x + threadIdx.x;
  if (i < EE) {
    int pos = atomicAdd(&cur[dst[i]], 1);
    const float* ea = eattr + i * 6;
    int4* q = (int4*)(pairs + pos);
    int4 w0, w1;
    w0.x = src[i] * 1024; w0.y = 0;
    w0.z = __float_as_int(ea[0]); w0.w = __float_as_int(ea[1]);
    w1.x = __float_as_int(ea[2]); w1.y = __float_as_int(ea[3]);
    w1.z = __float_as_int(ea[4]); w1.w = __float_as_int(ea[5]);
    q[0] = w0; q[1] = w1;
  }
}

// ---------------------------------------------------------------------------
// bf16 MFMA GEMM, 128 x (NS*128) tile, BK=64, 256 threads (2x2 waves; each
// wave covers NS 64-col slabs). More MFMA per barrier for skinny-N shapes;
// A-tile traffic amortized over 2x columns when NS=2. B direct from global
// (L2-resident weights); LDS only for A (18.4 KB, 2-way bank alias = free).
// ---------------------------------------------------------------------------
#define APAD 72

template <int NS>
__global__ __launch_bounds__(256) void gemm_bf16_v3(
    const short* __restrict__ A,   // [M][K] bf16
    const short* __restrict__ Bt,  // [N][K] bf16 (transposed weights)
    short* __restrict__ Cbf,       // [M][N] bf16
    int M, int N, int K) {
  __shared__ short As[128][APAD];
  const int tid  = threadIdx.x;
  const int wave = tid >> 6;
  const int lane = tid & 63;
  const int quad = lane >> 4;
  const int l16  = lane & 15;
  const int wr   = wave >> 1;
  const int wc   = wave & 1;
  const int bm = blockIdx.x * 128;
  const int bn = blockIdx.y * (128 * NS);

  const int srow = tid >> 3;
  const int skc  = (tid & 7) * 8;

  const short* Bw[NS];
  #pragma unroll
  for (int s = 0; s < NS; s++)
    Bw[s] = Bt + (size_t)(bn + s * 128 + wc * 64 + l16) * K + quad * 8;

  f32x4 acc[NS][4][4];
  #pragma unroll
  for (int s = 0; s < NS; s++)
    #pragma unroll
    for (int i = 0; i < 4; i++)
      #pragma unroll
      for (int jj = 0; jj < 4; jj++) acc[s][i][jj] = (f32x4){0, 0, 0, 0};

  for (int k0 = 0; k0 < K; k0 += 64) {
    #pragma unroll
    for (int i = 0; i < 4; i++) {
      int r = srow + i * 32;
      int gm = bm + r;
      int4 av = {0, 0, 0, 0};
      if (gm < M) av = *(const int4*)(A + (size_t)gm * K + k0 + skc);
      *(int4*)(&As[r][skc]) = av;
    }
    __syncthreads();

    #pragma unroll
    for (int kq = 0; kq < 2; kq++) {
      bf16x8 af[4];
      #pragma unroll
      for (int mi = 0; mi < 4; mi++)
        af[mi] = *(const bf16x8*)(&As[wr * 64 + mi * 16 + l16][kq * 32 + quad * 8]);
      #pragma unroll
      for (int s = 0; s < NS; s++) {
        bf16x8 bfr[4];
        #pragma unroll
        for (int ni = 0; ni < 4; ni++)
          bfr[ni] = *(const bf16x8*)(Bw[s] + (size_t)(ni * 16) * K + k0 + kq * 32);
        #pragma unroll
        for (int mi = 0; mi < 4; mi++)
          #pragma unroll
          for (int ni = 0; ni < 4; ni++)
            acc[s][mi][ni] = __builtin_amdgcn_mfma_f32_16x16x32_bf16(af[mi], bfr[ni], acc[s][mi][ni], 0, 0, 0);
      }
    }
    __syncthreads();
  }

  #pragma unroll
  for (int mi = 0; mi < 4; mi++) {
    #pragma unroll
    for (int r = 0; r < 4; r++) {
      int gm = bm + wr * 64 + mi * 16 + quad * 4 + r;
      if (gm < M) {
        #pragma unroll
        for (int s = 0; s < NS; s++)
          #pragma unroll
          for (int ni = 0; ni < 4; ni++)
            Cbf[(size_t)gm * N + bn + s * 128 + wc * 64 + ni * 16 + l16] = f2bf(acc[s][mi][ni][r]);
      }
    }
  }
}

// ---------------------------------------------------------------------------
// Fused GATv2 edge phase. wave = head; 4 edge-slots x 16 lanes x 4 channels.
// Per iteration: 2x dwordx4 EPack load (src offset + edge feats, ONE address
// stream) + 1 xs bf16x4 gather. No clamp (pairs padded +16 zero entries).
// Each wave processes 2 nodes sequentially (preamble amortized). Packed-fp32
// math; max-free softmax (logits O(1)). Output bf16.
// ---------------------------------------------------------------------------
template <int H, int CHS, int SOFF_SHR>
__global__ __launch_bounds__(H * 64) void gat_fused4(
    const short* __restrict__ xs, const short* __restrict__ xd,
    const EPack* __restrict__ pairs, const float* __restrict__ w_edge,
    const float* __restrict__ att, const float* __restrict__ bias,
    const int* __restrict__ offs, short* __restrict__ out_bf) {
  constexpr int CH = H * 64;
  const int tid  = threadIdx.x;
  const int head = tid >> 6;
  const int lane = tid & 63;
  const int slot = lane >> 4;
  const int pos  = lane & 15;
  const int ch   = head * 64 + pos * 4;

  const f32x4 attf = *(const f32x4*)(att + ch);
  f32x4 wef[6];
  #pragma unroll
  for (int k = 0; k < 6; k++) wef[k] = *(const f32x4*)(w_edge + k * CH + ch);
  const f32x4 b4 = *(const f32x4*)(bias + ch);

  const char* xs_b = (const char*)xs + ch * 2;

  #pragma unroll
  for (int nn = 0; nn < 2; nn++) {
    const int n = blockIdx.x * 2 + nn;
    if (n >= NN) break;

    uint2 xdr = *(const uint2*)(xd + (size_t)n * CHS + ch);
    f32x2 xd01, xd23; bf4_unpack(xdr, xd01, xd23);

    const int beg = offs[n], end = offs[n + 1];
    float l = 0.f;
    f32x2 acc01 = {0, 0}, acc23 = {0, 0};

    if (beg < end) {
      const int niter = (end - beg + 3) >> 2;
      int idx = beg + slot;
      bool v = idx < end;
      // prefetch (padded array: no clamp needed)
      const int4* pp = (const int4*)(pairs + idx);
      int4 a = pp[0], b = pp[1];
      uint2 xr = *(const uint2*)(xs_b + ((unsigned)a.x >> SOFF_SHR));

      for (int it = 0; it < niter; it++) {
        int4 ac = a, bc = b;
        uint2 xrc = xr;
        bool vc = v;
        idx += 4;
        v = idx < end;
        pp = (const int4*)(pairs + idx);
        a = pp[0]; b = pp[1];
        xr = *(const uint2*)(xs_b + ((unsigned)a.x >> SOFF_SHR));

        f32x2 x01, x23; bf4_unpack(xrc, x01, x23);
        f32x2 e01 = {__int_as_float(ac.z), __int_as_float(ac.w)};
        f32x2 e23 = {__int_as_float(bc.x), __int_as_float(bc.y)};
        f32x2 e45 = {__int_as_float(bc.z), __int_as_float(bc.w)};
        f32x2 z01 = x01 + xd01, z23 = x23 + xd23;
        z01 = __builtin_elementwise_fma((f32x2)(e01.x), wef[0].xy, z01);
        z23 = __builtin_elementwise_fma((f32x2)(e01.x), wef[0].zw, z23);
        z01 = __builtin_elementwise_fma((f32x2)(e01.y), wef[1].xy, z01);
        z23 = __builtin_elementwise_fma((f32x2)(e01.y), wef[1].zw, z23);
        z01 = __builtin_elementwise_fma((f32x2)(e23.x), wef[2].xy, z01);
        z23 = __builtin_elementwise_fma((f32x2)(e23.x), wef[2].zw, z23);
        z01 = __builtin_elementwise_fma((f32x2)(e23.y), wef[3].xy, z01);
        z23 = __builtin_elementwise_fma((f32x2)(e23.y), wef[3].zw, z23);
        z01 = __builtin_elementwise_fma((f32x2)(e45.x), wef[4].xy, z01);
        z23 = __builtin_elementwise_fma((f32x2)(e45.x), wef[4].zw, z23);
        z01 = __builtin_elementwise_fma((f32x2)(e45.y), wef[5].xy, z01);
        z23 = __builtin_elementwise_fma((f32x2)(e45.y), wef[5].zw, z23);
        z01 = __builtin_elementwise_max(z01, z01 * 0.2f);
        z23 = __builtin_elementwise_max(z23, z23 * 0.2f);
        f32x2 d = z01 * attf.xy;
        d = __builtin_elementwise_fma(z23, attf.zw, d);
        float p = d.x + d.y;
        #pragma unroll
        for (int off = 1; off < 16; off <<= 1) p += __shfl_xor(p, off, 64);

        float w = vc ? __expf(p) : 0.f;
        l += w;
        acc01 = __builtin_elementwise_fma((f32x2)w, x01, acc01);
        acc23 = __builtin_elementwise_fma((f32x2)w, x23, acc23);
      }
    }

    // merge the 4 slots (plain sums)
    #pragma unroll
    for (int d = 16; d <= 32; d <<= 1) {
      l       += __shfl_xor(l, d, 64);
      acc01.x += __shfl_xor(acc01.x, d, 64);
      acc01.y += __shfl_xor(acc01.y, d, 64);
      acc23.x += __shfl_xor(acc23.x, d, 64);
      acc23.y += __shfl_xor(acc23.y, d, 64);
    }

    if (slot == 0) {
      float inv = 1.f / (l + 1e-16f);
      float v0 = acc01.x * inv + b4.x;
      float v1 = acc01.y * inv + b4.y;
      float v2 = acc23.x * inv + b4.z;
      float v3 = acc23.y * inv + b4.w;
      v0 = v0 > 0.f ? v0 : (__expf(v0) - 1.f);
      v1 = v1 > 0.f ? v1 : (__expf(v1) - 1.f);
      v2 = v2 > 0.f ? v2 : (__expf(v2) - 1.f);
      v3 = v3 > 0.f ? v3 : (__expf(v3) - 1.f);
      short4 o;
      o.x = f2bf(v0); o.y = f2bf(v1); o.z = f2bf(v2); o.w = f2bf(v3);
      *(short4*)(out_bf + (size_t)n * CH + ch) = o;
    }
  }
}

// Layer-3 + pool variant (H=1, CHS=128, soff>>2): wave = node, 2 nodes per
// wave, 4 waves per block. global_add_pool fused via fp32 atomics.
__global__ __launch_bounds__(256) void gat_fused_pool4(
    const short* __restrict__ xs, const short* __restrict__ xd,
    const EPack* __restrict__ pairs, const float* __restrict__ w_edge,
    const float* __restrict__ att, const float* __restrict__ bias,
    const int* __restrict__ offs, const int* __restrict__ batch,
    float* __restrict__ gp) {
  constexpr int CHS = 128;
  const int lane = threadIdx.x & 63;
  const int slot = lane >> 4;
  const int pos  = lane & 15;
  const int ch   = pos * 4;
  const int nbase = blockIdx.x * 8 + (threadIdx.x >> 6) * 2;

  const f32x4 attf = *(const f32x4*)(att + ch);
  f32x4 wef[6];
  #pragma unroll
  for (int k = 0; k < 6; k++) wef[k] = *(const f32x4*)(w_edge + k * 64 + ch);
  const f32x4 b4 = *(const f32x4*)(bias + ch);

  const char* xs_b = (const char*)xs + ch * 2;

  #pragma unroll
  for (int nn = 0; nn < 2; nn++) {
    const int n = nbase + nn;
    if (n >= NN) break;

    uint2 xdr = *(const uint2*)(xd + (size_t)n * CHS + ch);
    f32x2 xd01, xd23; bf4_unpack(xdr, xd01, xd23);

    const int beg = offs[n], end = offs[n + 1];
    float l = 0.f;
    f32x2 acc01 = {0, 0}, acc23 = {0, 0};

    if (beg < end) {
      const int niter = (end - beg + 3) >> 2;
      int idx = beg + slot;
      bool v = idx < end;
      const int4* pp = (const int4*)(pairs + idx);
      int4 a = pp[0], b = pp[1];
      uint2 xr = *(const uint2*)(xs_b + ((unsigned)a.x >> 2));

      for (int it = 0; it < niter; it++) {
        int4 ac = a, bc = b;
        uint2 xrc = xr;
        bool vc = v;
        idx += 4;
        v = idx < end;
        pp = (const int4*)(pairs + idx);
        a = pp[0]; b = pp[1];
        xr = *(const uint2*)(xs_b + ((unsigned)a.x >> 2));

        f32x2 x01, x23; bf4_unpack(xrc, x01, x23);
        f32x2 e01 = {__int_as_float(ac.z), __int_as_float(ac.w)};
        f32x2 e23 = {__int_as_float(bc.x), __int_as_float(bc.y)};
        f32x2 e45 = {__int_as_float(bc.z), __int_as_float(bc.w)};
        f32x2 z01 = x01 + xd01, z23 = x23 + xd23;
        z01 = __builtin_elementwise_fma((f32x2)(e01.x), wef[0].xy, z01);
        z23 = __builtin_elementwise_fma((f32x2)(e01.x), wef[0].zw, z23);
        z01 = __builtin_elementwise_fma((f32x2)(e01.y), wef[1].xy, z01);
        z23 = __builtin_elementwise_fma((f32x2)(e01.y), wef[1].zw, z23);
        z01 = __builtin_elementwise_fma((f32x2)(e23.x), wef[2].xy, z01);
        z23 = __builtin_elementwise_fma((f32x2)(e23.x), wef[2].zw, z23);
        z01 = __builtin_elementwise_fma((f32x2)(e23.y), wef[3].xy, z01);
        z23 = __builtin_elementwise_fma((f32x2)(e23.y), wef[3].zw, z23);
        z01 = __builtin_elementwise_fma((f32x2)(e45.x), wef[4].xy, z01);
        z23 = __builtin_elementwise_fma((f32x2)(e45.x), wef[4].zw, z23);
        z01 = __builtin_elementwise_fma((f32x2)(e45.y), wef[5].xy, z01);
        z23 = __builtin_elementwise_fma((f32x2)(e45.y), wef[5].zw, z23);
        z01 = __builtin_elementwise_max(z01, z01 * 0.2f);
        z23 = __builtin_elementwise_max(z23, z23 * 0.2f);
        f32x2 d = z01 * attf.xy;
        d = __builtin_elementwise_fma(z23, attf.zw, d);
        float p = d.x + d.y;
        #pragma unroll
        for (int off = 1; off < 16; off <<= 1) p += __shfl_xor(p, off, 64);

        float w = vc ? __expf(p) : 0.f;
        l += w;
        acc01 = __builtin_elementwise_fma((f32x2)w, x01, acc01);
        acc23 = __builtin_elementwise_fma((f32x2)w, x23, acc23);
      }
    }

    #pragma unroll
    for (int d = 16; d <= 32; d <<= 1) {
      l       += __shfl_xor(l, d, 64);
      acc01.x += __shfl_xor(acc01.x, d, 64);
      acc01.y += __shfl_xor(acc01.y, d, 64);
      acc23.x += __shfl_xor(acc23.x, d, 64);
      acc23.y += __shfl_xor(acc23.y, d, 64);
    }

    if (slot == 0) {
      float inv = 1.f / (l + 1e-16f);
      float v0 = acc01.x * inv + b4.x;
      float v1 = acc01.y * inv + b4.y;
      float v2 = acc23.x * inv + b4.z;
      float v3 = acc23.y * inv + b4.w;
      v0 = v0 > 0.f ? v0 : (__expf(v0) - 1.f);
      v1 = v1 > 0.f ? v1 : (__expf(v1) - 1.f);
      v2 = v2 > 0.f ? v2 : (__expf(v2) - 1.f);
      v3 = v3 > 0.f ? v3 : (__expf(v3) - 1.f);
      float* g = gp + (size_t)batch[n] * 64 + ch;
      atomicAdd(g + 0, v0);
      atomicAdd(g + 1, v1);
      atomicAdd(g + 2, v2);
      atomicAdd(g + 3, v3);
    }
  }
}

// ---------------------------------------------------------------------------
// MLP head: out[g] = elu(g_row @ fc1 + b) @ out_w + out_b. One wave per graph.
// ---------------------------------------------------------------------------
__global__ __launch_bounds__(64) void head_mlp(const float* __restrict__ gpool,
                                               const float* __restrict__ fc1_w,
                                               const float* __restrict__ fc1_b,
                                               const float* __restrict__ out_w,
                                               const float* __restrict__ out_b,
                                               float* __restrict__ out) {
  int gr = blockIdx.x;
  int c = threadIdx.x;
  float acc = fc1_b[c];
  #pragma unroll 8
  for (int k = 0; k < HIDC; k++)
    acc += gpool[gr * HIDC + k] * fc1_w[k * HIDC + c];
  acc = acc > 0.f ? acc : (__expf(acc) - 1.f);
  float v = acc * out_w[c];
  #pragma unroll
  for (int off = 32; off > 0; off >>= 1) v += __shfl_xor(v, off, 64);
  if (c == 0) out[gr] = v + out_b[0];
}

// ---------------------------------------------------------------------------
// Host launch
// ---------------------------------------------------------------------------
extern "C" void kernel_launch(void* const* d_in, const int* in_sizes, int n_in,
                              void* d_out, int out_size, void* d_ws, size_t ws_size,
                              hipStream_t stream) {
  const float* x      = (const float*)d_in[0];
  const int*   ei     = (const int*)d_in[1];
  const float* eattr  = (const float*)d_in[2];
  const int*   batch  = (const int*)d_in[3];
  const float* w_src1 = (const float*)d_in[4];
  const float* w_dst1 = (const float*)d_in[5];
  const float* w_edge1= (const float*)d_in[6];
  const float* att1   = (const float*)d_in[7];
  const float* b1     = (const float*)d_in[8];
  const float* w_src2 = (const float*)d_in[9];
  const float* w_dst2 = (const float*)d_in[10];
  const float* w_edge2= (const float*)d_in[11];
  const float* att2   = (const float*)d_in[12];
  const float* b2     = (const float*)d_in[13];
  const float* w_src3 = (const float*)d_in[14];
  const float* w_dst3 = (const float*)d_in[15];
  const float* w_edge3= (const float*)d_in[16];
  const float* att3   = (const float*)d_in[17];
  const float* b3     = (const float*)d_in[18];
  const float* fc1_w  = (const float*)d_in[19];
  const float* fc1_b  = (const float*)d_in[20];
  const float* out_w  = (const float*)d_in[21];
  const float* out_b  = (const float*)d_in[22];

  const int* src = ei;
  const int* dst = ei + EE;

  char* p = (char*)d_ws;
  auto carve = [&](size_t bytes) -> void* {
    void* r = (void*)p;
    p += (bytes + 255) & ~(size_t)255;
    return r;
  };
  short* xsd_bf = (short*)carve((size_t)NN * 512 * sizeof(short));  // 51.2 MB bf16 [xs|xd]
  short* xbf1   = (short*)carve((size_t)NN * FF * sizeof(short));   // 12.8 MB
  short* hbf    = (short*)carve((size_t)NN * HC * sizeof(short));   // 25.6 MB
  short* wtcat1 = (short*)carve((size_t)512 * FF * sizeof(short));
  short* wtcat2 = (short*)carve((size_t)512 * HC * sizeof(short));
  short* wtcat3 = (short*)carve((size_t)128 * HC * sizeof(short));
  float* gp     = (float*)carve((size_t)GG * HIDC * sizeof(float));
  int* deg      = (int*)carve((size_t)NN * sizeof(int));
  int* offs     = (int*)carve((size_t)(NN + 1) * sizeof(int));
  int* cur      = (int*)carve((size_t)NN * sizeof(int));
  EPack* pairs  = (EPack*)carve((size_t)(EE + 16) * sizeof(EPack)); // 16 MB
  (void)ws_size; (void)n_in; (void)in_sizes; (void)out_size;

  const int GM128 = (NN + 127) / 128;  // 391

  // --- Prep: zero deg/gp/pairs-tail, cvt x, cvt all weights (ONE dispatch) ---
  WtJobs j;
  j.w[0] = w_src1; j.o[0] = wtcat1;                       j.K[0] = FF; j.N[0] = HC;
  j.w[1] = w_dst1; j.o[1] = wtcat1 + (size_t)HC * FF;     j.K[1] = FF; j.N[1] = HC;
  j.w[2] = w_src2; j.o[2] = wtcat2;                       j.K[2] = HC; j.N[2] = HC;
  j.w[3] = w_dst2; j.o[3] = wtcat2 + (size_t)HC * HC;     j.K[3] = HC; j.N[3] = HC;
  j.w[4] = w_src3; j.o[4] = wtcat3;                       j.K[4] = HC; j.N[4] = HIDC;
  j.w[5] = w_dst3; j.o[5] = wtcat3 + (size_t)HIDC * HC;   j.K[5] = HC; j.N[5] = HIDC;
  j.cum[0] = 0;
  for (int s = 0; s < 6; s++) j.cum[s + 1] = j.cum[s] + j.K[s] * j.N[s];
  prep_all<<<(NN * FF + 255) / 256, 256, 0, stream>>>(x, xbf1, deg, gp,
                                                      (int*)(pairs + EE), j);

  // --- CSR build (shared by all layers) ---
  count_deg<<<(EE + 255) / 256, 256, 0, stream>>>(dst, deg);
  scan_offs<<<1, 1024, 0, stream>>>(deg, offs, cur);
  fill_edges<<<(EE + 255) / 256, 256, 0, stream>>>(src, dst, eattr, cur, pairs);

  // --- Layer 1: one GEMM for [xs|xd] (N=512, K=128), 128x256 tiles ---
  gemm_bf16_v3<2><<<dim3(GM128, 2), 256, 0, stream>>>(xbf1, wtcat1, xsd_bf, NN, 512, FF);
  gat_fused4<NHEAD, 512, 0><<<(NN + 1) / 2, HC, 0, stream>>>(xsd_bf, xsd_bf + HC, pairs,
                                                             w_edge1, att1, b1, offs, hbf);

  // --- Layer 2: N=512, K=256, 128x256 tiles ---
  gemm_bf16_v3<2><<<dim3(GM128, 2), 256, 0, stream>>>(hbf, wtcat2, xsd_bf, NN, 512, HC);
  gat_fused4<NHEAD, 512, 0><<<(NN + 1) / 2, HC, 0, stream>>>(xsd_bf, xsd_bf + HC, pairs,
                                                             w_edge2, att2, b2, offs, hbf);

  // --- Layer 3: N=128, K=256; fused pool (8 nodes/block, 2 per wave) ---
  gemm_bf16_v3<1><<<dim3(GM128, 1), 256, 0, stream>>>(hbf, wtcat3, xsd_bf, NN, 128, HC);
  gat_fused_pool4<<<(NN + 7) / 8, 256, 0, stream>>>(xsd_bf, xsd_bf + HIDC, pairs,
                                                    w_edge3, att3, b3, offs, batch, gp);

  // --- MLP head ---
  head_mlp<<<GG, 64, 0, stream>>>(gp, fc1_w, fc1_b, out_w, out_b, (float*)d_out);
}

// Round 11
// 708.521 us; speedup vs baseline: 1.0628x; 1.0628x over previous
//
#include <hip/hip_runtime.h>
#include <hip/hip_bf16.h>
#include <cstddef>
#include <cstdint>

// Problem constants (match reference setup_inputs)
constexpr int NN    = 50000;   // nodes
constexpr int EE    = 500000;  // edges
constexpr int FF    = 128;     // input feature dim
constexpr int HIDC  = 64;      // hidden per head
constexpr int NHEAD = 4;
constexpr int HC    = 256;     // NHEAD * HIDC
constexpr int GG    = 256;     // graphs

typedef __attribute__((ext_vector_type(2))) float f32x2;
typedef __attribute__((ext_vector_type(4))) float f32x4;
typedef __attribute__((ext_vector_type(8))) short bf16x8;

// CSR edge record: src byte-offset (src*1024) + the 6 edge features. 32 B.
struct __align__(16) EPack { int soff; int pad; float e0, e1, e2, e3, e4, e5; };

// round-to-nearest-even fp32 -> bf16 (as short)
__device__ inline short f2bf(float f) {
  union { float f; unsigned u; } v; v.f = f;
  unsigned r = v.u + 0x7fffu + ((v.u >> 16) & 1u);
  return (short)(r >> 16);
}

// unpack 4 bf16 (as uint2) -> two f32x2
__device__ inline void bf4_unpack(uint2 v, f32x2& a, f32x2& b) {
  union { unsigned u; float f; } t;
  t.u = v.x << 16;          a.x = t.f;
  t.u = v.x & 0xffff0000u;  a.y = t.f;
  t.u = v.y << 16;          b.x = t.f;
  t.u = v.y & 0xffff0000u;  b.y = t.f;
}

// ---------------------------------------------------------------------------
// Weight-conversion job table (all 6 matrices)
// ---------------------------------------------------------------------------
struct WtJobs {
  const float* w[6];
  short* o[6];
  int K[6], N[6];
  int cum[7];
};

// ---------------------------------------------------------------------------
// Prep kernel: zero deg + gp + pairs tail, convert x -> bf16, convert all
// weights (transpose+bf16). One dispatch replaces 5.
// ---------------------------------------------------------------------------
__global__ void prep_all(const float* __restrict__ x, short* __restrict__ xbf,
                         int* __restrict__ deg, float* __restrict__ gp,
                         int* __restrict__ pairs_tail, WtJobs j) {
  int i = blockIdx.x * blockDim.x + threadIdx.x;
  if (i < NN * FF) xbf[i] = f2bf(x[i]);
  if (i < NN) deg[i] = 0;
  if (i < GG * HIDC) gp[i] = 0.f;
  if (i < 16 * 8) pairs_tail[i] = 0;           // 16 EPack tail entries
  if (i < j.cum[6]) {
    int s = 0;
    while (i >= j.cum[s + 1]) s++;
    int li = i - j.cum[s];
    int K = j.K[s], N = j.N[s];
    int n = li / K, k = li - n * K;
    j.o[s][li] = f2bf(j.w[s][k * N + n]);
  }
}

// ---------------------------------------------------------------------------
// CSR build (by destination node)
// ---------------------------------------------------------------------------
__global__ void count_deg(const int* __restrict__ dst, int* __restrict__ deg) {
  int i = blockIdx.x * blockDim.x + threadIdx.x;
  if (i < EE) atomicAdd(&deg[dst[i]], 1);
}

__global__ __launch_bounds__(1024) void scan_offs(const int* __restrict__ deg,
                                                  int* __restrict__ offs,
                                                  int* __restrict__ cur) {
  __shared__ int sums[1024];
  int t = threadIdx.x;
  const int chunk = (NN + 1023) / 1024;
  int beg = t * chunk;
  int end = beg + chunk; if (end > NN) end = NN; if (beg > NN) beg = NN;
  int s = 0;
  for (int i = beg; i < end; i++) s += deg[i];
  sums[t] = s;
  __syncthreads();
  for (int off = 1; off < 1024; off <<= 1) {
    int v = (t >= off) ? sums[t - off] : 0;
    __syncthreads();
    sums[t] += v;
    __syncthreads();
  }
  int run = (t == 0) ? 0 : sums[t - 1];
  for (int i = beg; i < end; i++) {
    offs[i] = run; cur[i] = run; run += deg[i];
  }
  if (t == 1023) offs[NN] = run;
}

__global__ void fill_edges(const int* __restrict__ src, const int* __restrict__ dst,
                           const float* __restrict__ eattr,
                           int* __restrict__ cur, EPack* __restrict__ pairs) {
  int i = blockIdx.x * blockDim.x + threadIdx.x;
  if (i < EE) {
    int pos = atomicAdd(&cur[dst[i]], 1);
    const float* ea = eattr + i * 6;
    int4* q = (int4*)(pairs + pos);
    int4 w0, w1;
    w0.x = src[i] * 1024; w0.y = 0;
    w0.z = __float_as_int(ea[0]); w0.w = __float_as_int(ea[1]);
    w1.x = __float_as_int(ea[2]); w1.y = __float_as_int(ea[3]);
    w1.z = __float_as_int(ea[4]); w1.w = __float_as_int(ea[5]);
    q[0] = w0; q[1] = w1;
  }
}

// ---------------------------------------------------------------------------
// bf16 MFMA GEMM, 128x128 tile, BK=64, 256 threads (2x2 waves of 64x64).
// B fragments direct from global (L2-resident weights); LDS only for A.
// (R8-proven version: 1564-block grid for N=512 — do not shrink the grid.)
// ---------------------------------------------------------------------------
#define APAD 72

__global__ __launch_bounds__(256) void gemm_bf16_v2(
    const short* __restrict__ A,   // [M][K] bf16
    const short* __restrict__ Bt,  // [N][K] bf16 (transposed weights)
    short* __restrict__ Cbf,       // [M][N] bf16
    int M, int N, int K) {
  __shared__ short As[128][APAD];
  const int tid  = threadIdx.x;
  const int wave = tid >> 6;
  const int lane = tid & 63;
  const int quad = lane >> 4;
  const int l16  = lane & 15;
  const int wr   = wave >> 1;
  const int wc   = wave & 1;
  const int bm = blockIdx.x * 128;
  const int bn = blockIdx.y * 128;

  const int srow = tid >> 3;
  const int skc  = (tid & 7) * 8;

  const short* Bw = Bt + (size_t)(bn + wc * 64 + l16) * K + quad * 8;

  f32x4 acc[4][4];
  #pragma unroll
  for (int i = 0; i < 4; i++)
    #pragma unroll
    for (int jj = 0; jj < 4; jj++) acc[i][jj] = (f32x4){0, 0, 0, 0};

  for (int k0 = 0; k0 < K; k0 += 64) {
    #pragma unroll
    for (int i = 0; i < 4; i++) {
      int r = srow + i * 32;
      int gm = bm + r;
      int4 av = {0, 0, 0, 0};
      if (gm < M) av = *(const int4*)(A + (size_t)gm * K + k0 + skc);
      *(int4*)(&As[r][skc]) = av;
    }
    __syncthreads();

    #pragma unroll
    for (int kq = 0; kq < 2; kq++) {
      bf16x8 bfr[4];
      #pragma unroll
      for (int ni = 0; ni < 4; ni++)
        bfr[ni] = *(const bf16x8*)(Bw + (size_t)(ni * 16) * K + k0 + kq * 32);
      bf16x8 af[4];
      #pragma unroll
      for (int mi = 0; mi < 4; mi++)
        af[mi] = *(const bf16x8*)(&As[wr * 64 + mi * 16 + l16][kq * 32 + quad * 8]);
      #pragma unroll
      for (int mi = 0; mi < 4; mi++)
        #pragma unroll
        for (int ni = 0; ni < 4; ni++)
          acc[mi][ni] = __builtin_amdgcn_mfma_f32_16x16x32_bf16(af[mi], bfr[ni], acc[mi][ni], 0, 0, 0);
    }
    __syncthreads();
  }

  #pragma unroll
  for (int mi = 0; mi < 4; mi++) {
    #pragma unroll
    for (int r = 0; r < 4; r++) {
      int gm = bm + wr * 64 + mi * 16 + quad * 4 + r;
      if (gm < M) {
        #pragma unroll
        for (int ni = 0; ni < 4; ni++)
          Cbf[(size_t)gm * N + bn + wc * 64 + ni * 16 + l16] = f2bf(acc[mi][ni][r]);
      }
    }
  }
}

// ---------------------------------------------------------------------------
// Fused GATv2 edge phase. wave = head; 4 edge-slots x 16 lanes x 4 channels.
// Per iteration: 2x dwordx4 EPack load (src offset + edge feats, ONE address
// stream) + 1 xs bf16x4 gather. No clamp (pairs padded +16 zero entries).
// Each wave processes 4 nodes sequentially (preamble/ramp amortized).
// Packed-fp32 math; max-free softmax (logits O(1)). Output bf16.
// ---------------------------------------------------------------------------
template <int H, int CHS, int SOFF_SHR>
__global__ __launch_bounds__(H * 64) void gat_fused4(
    const short* __restrict__ xs, const short* __restrict__ xd,
    const EPack* __restrict__ pairs, const float* __restrict__ w_edge,
    const float* __restrict__ att, const float* __restrict__ bias,
    const int* __restrict__ offs, short* __restrict__ out_bf) {
  constexpr int CH = H * 64;
  const int tid  = threadIdx.x;
  const int head = tid >> 6;
  const int lane = tid & 63;
  const int slot = lane >> 4;
  const int pos  = lane & 15;
  const int ch   = head * 64 + pos * 4;

  const f32x4 attf = *(const f32x4*)(att + ch);
  f32x4 wef[6];
  #pragma unroll
  for (int k = 0; k < 6; k++) wef[k] = *(const f32x4*)(w_edge + k * CH + ch);
  const f32x4 b4 = *(const f32x4*)(bias + ch);

  const char* xs_b = (const char*)xs + ch * 2;

  #pragma unroll
  for (int nn = 0; nn < 4; nn++) {
    const int n = blockIdx.x * 4 + nn;
    if (n >= NN) break;

    uint2 xdr = *(const uint2*)(xd + (size_t)n * CHS + ch);
    f32x2 xd01, xd23; bf4_unpack(xdr, xd01, xd23);

    const int beg = offs[n], end = offs[n + 1];
    float l = 0.f;
    f32x2 acc01 = {0, 0}, acc23 = {0, 0};

    if (beg < end) {
      const int niter = (end - beg + 3) >> 2;
      int idx = beg + slot;
      bool v = idx < end;
      // prefetch (padded array: no clamp needed)
      const int4* pp = (const int4*)(pairs + idx);
      int4 a = pp[0], b = pp[1];
      uint2 xr = *(const uint2*)(xs_b + ((unsigned)a.x >> SOFF_SHR));

      for (int it = 0; it < niter; it++) {
        int4 ac = a, bc = b;
        uint2 xrc = xr;
        bool vc = v;
        idx += 4;
        v = idx < end;
        pp = (const int4*)(pairs + idx);
        a = pp[0]; b = pp[1];
        xr = *(const uint2*)(xs_b + ((unsigned)a.x >> SOFF_SHR));

        f32x2 x01, x23; bf4_unpack(xrc, x01, x23);
        f32x2 e01 = {__int_as_float(ac.z), __int_as_float(ac.w)};
        f32x2 e23 = {__int_as_float(bc.x), __int_as_float(bc.y)};
        f32x2 e45 = {__int_as_float(bc.z), __int_as_float(bc.w)};
        f32x2 z01 = x01 + xd01, z23 = x23 + xd23;
        z01 = __builtin_elementwise_fma((f32x2)(e01.x), wef[0].xy, z01);
        z23 = __builtin_elementwise_fma((f32x2)(e01.x), wef[0].zw, z23);
        z01 = __builtin_elementwise_fma((f32x2)(e01.y), wef[1].xy, z01);
        z23 = __builtin_elementwise_fma((f32x2)(e01.y), wef[1].zw, z23);
        z01 = __builtin_elementwise_fma((f32x2)(e23.x), wef[2].xy, z01);
        z23 = __builtin_elementwise_fma((f32x2)(e23.x), wef[2].zw, z23);
        z01 = __builtin_elementwise_fma((f32x2)(e23.y), wef[3].xy, z01);
        z23 = __builtin_elementwise_fma((f32x2)(e23.y), wef[3].zw, z23);
        z01 = __builtin_elementwise_fma((f32x2)(e45.x), wef[4].xy, z01);
        z23 = __builtin_elementwise_fma((f32x2)(e45.x), wef[4].zw, z23);
        z01 = __builtin_elementwise_fma((f32x2)(e45.y), wef[5].xy, z01);
        z23 = __builtin_elementwise_fma((f32x2)(e45.y), wef[5].zw, z23);
        z01 = __builtin_elementwise_max(z01, z01 * 0.2f);
        z23 = __builtin_elementwise_max(z23, z23 * 0.2f);
        f32x2 d = z01 * attf.xy;
        d = __builtin_elementwise_fma(z23, attf.zw, d);
        float p = d.x + d.y;
        #pragma unroll
        for (int off = 1; off < 16; off <<= 1) p += __shfl_xor(p, off, 64);

        float w = vc ? __expf(p) : 0.f;
        l += w;
        acc01 = __builtin_elementwise_fma((f32x2)w, x01, acc01);
        acc23 = __builtin_elementwise_fma((f32x2)w, x23, acc23);
      }
    }

    // merge the 4 slots (plain sums)
    #pragma unroll
    for (int d = 16; d <= 32; d <<= 1) {
      l       += __shfl_xor(l, d, 64);
      acc01.x += __shfl_xor(acc01.x, d, 64);
      acc01.y += __shfl_xor(acc01.y, d, 64);
      acc23.x += __shfl_xor(acc23.x, d, 64);
      acc23.y += __shfl_xor(acc23.y, d, 64);
    }

    if (slot == 0) {
      float inv = 1.f / (l + 1e-16f);
      float v0 = acc01.x * inv + b4.x;
      float v1 = acc01.y * inv + b4.y;
      float v2 = acc23.x * inv + b4.z;
      float v3 = acc23.y * inv + b4.w;
      v0 = v0 > 0.f ? v0 : (__expf(v0) - 1.f);
      v1 = v1 > 0.f ? v1 : (__expf(v1) - 1.f);
      v2 = v2 > 0.f ? v2 : (__expf(v2) - 1.f);
      v3 = v3 > 0.f ? v3 : (__expf(v3) - 1.f);
      short4 o;
      o.x = f2bf(v0); o.y = f2bf(v1); o.z = f2bf(v2); o.w = f2bf(v3);
      *(short4*)(out_bf + (size_t)n * CH + ch) = o;
    }
  }
}

// Layer-3 + pool variant (H=1, CHS=128, soff>>2): wave = node, 4 nodes per
// wave, 4 waves per block. global_add_pool fused via fp32 atomics.
__global__ __launch_bounds__(256) void gat_fused_pool4(
    const short* __restrict__ xs, const short* __restrict__ xd,
    const EPack* __restrict__ pairs, const float* __restrict__ w_edge,
    const float* __restrict__ att, const float* __restrict__ bias,
    const int* __restrict__ offs, const int* __restrict__ batch,
    float* __restrict__ gp) {
  constexpr int CHS = 128;
  const int lane = threadIdx.x & 63;
  const int slot = lane >> 4;
  const int pos  = lane & 15;
  const int ch   = pos * 4;
  const int nbase = blockIdx.x * 16 + (threadIdx.x >> 6) * 4;

  const f32x4 attf = *(const f32x4*)(att + ch);
  f32x4 wef[6];
  #pragma unroll
  for (int k = 0; k < 6; k++) wef[k] = *(const f32x4*)(w_edge + k * 64 + ch);
  const f32x4 b4 = *(const f32x4*)(bias + ch);

  const char* xs_b = (const char*)xs + ch * 2;

  #pragma unroll
  for (int nn = 0; nn < 4; nn++) {
    const int n = nbase + nn;
    if (n >= NN) break;

    uint2 xdr = *(const uint2*)(xd + (size_t)n * CHS + ch);
    f32x2 xd01, xd23; bf4_unpack(xdr, xd01, xd23);

    const int beg = offs[n], end = offs[n + 1];
    float l = 0.f;
    f32x2 acc01 = {0, 0}, acc23 = {0, 0};

    if (beg < end) {
      const int niter = (end - beg + 3) >> 2;
      int idx = beg + slot;
      bool v = idx < end;
      const int4* pp = (const int4*)(pairs + idx);
      int4 a = pp[0], b = pp[1];
      uint2 xr = *(const uint2*)(xs_b + ((unsigned)a.x >> 2));

      for (int it = 0; it < niter; it++) {
        int4 ac = a, bc = b;
        uint2 xrc = xr;
        bool vc = v;
        idx += 4;
        v = idx < end;
        pp = (const int4*)(pairs + idx);
        a = pp[0]; b = pp[1];
        xr = *(const uint2*)(xs_b + ((unsigned)a.x >> 2));

        f32x2 x01, x23; bf4_unpack(xrc, x01, x23);
        f32x2 e01 = {__int_as_float(ac.z), __int_as_float(ac.w)};
        f32x2 e23 = {__int_as_float(bc.x), __int_as_float(bc.y)};
        f32x2 e45 = {__int_as_float(bc.z), __int_as_float(bc.w)};
        f32x2 z01 = x01 + xd01, z23 = x23 + xd23;
        z01 = __builtin_elementwise_fma((f32x2)(e01.x), wef[0].xy, z01);
        z23 = __builtin_elementwise_fma((f32x2)(e01.x), wef[0].zw, z23);
        z01 = __builtin_elementwise_fma((f32x2)(e01.y), wef[1].xy, z01);
        z23 = __builtin_elementwise_fma((f32x2)(e01.y), wef[1].zw, z23);
        z01 = __builtin_elementwise_fma((f32x2)(e23.x), wef[2].xy, z01);
        z23 = __builtin_elementwise_fma((f32x2)(e23.x), wef[2].zw, z23);
        z01 = __builtin_elementwise_fma((f32x2)(e23.y), wef[3].xy, z01);
        z23 = __builtin_elementwise_fma((f32x2)(e23.y), wef[3].zw, z23);
        z01 = __builtin_elementwise_fma((f32x2)(e45.x), wef[4].xy, z01);
        z23 = __builtin_elementwise_fma((f32x2)(e45.x), wef[4].zw, z23);
        z01 = __builtin_elementwise_fma((f32x2)(e45.y), wef[5].xy, z01);
        z23 = __builtin_elementwise_fma((f32x2)(e45.y), wef[5].zw, z23);
        z01 = __builtin_elementwise_max(z01, z01 * 0.2f);
        z23 = __builtin_elementwise_max(z23, z23 * 0.2f);
        f32x2 d = z01 * attf.xy;
        d = __builtin_elementwise_fma(z23, attf.zw, d);
        float p = d.x + d.y;
        #pragma unroll
        for (int off = 1; off < 16; off <<= 1) p += __shfl_xor(p, off, 64);

        float w = vc ? __expf(p) : 0.f;
        l += w;
        acc01 = __builtin_elementwise_fma((f32x2)w, x01, acc01);
        acc23 = __builtin_elementwise_fma((f32x2)w, x23, acc23);
      }
    }

    #pragma unroll
    for (int d = 16; d <= 32; d <<= 1) {
      l       += __shfl_xor(l, d, 64);
      acc01.x += __shfl_xor(acc01.x, d, 64);
      acc01.y += __shfl_xor(acc01.y, d, 64);
      acc23.x += __shfl_xor(acc23.x, d, 64);
      acc23.y += __shfl_xor(acc23.y, d, 64);
    }

    if (slot == 0) {
      float inv = 1.f / (l + 1e-16f);
      float v0 = acc01.x * inv + b4.x;
      float v1 = acc01.y * inv + b4.y;
      float v2 = acc23.x * inv + b4.z;
      float v3 = acc23.y * inv + b4.w;
      v0 = v0 > 0.f ? v0 : (__expf(v0) - 1.f);
      v1 = v1 > 0.f ? v1 : (__expf(v1) - 1.f);
      v2 = v2 > 0.f ? v2 : (__expf(v2) - 1.f);
      v3 = v3 > 0.f ? v3 : (__expf(v3) - 1.f);
      float* g = gp + (size_t)batch[n] * 64 + ch;
      atomicAdd(g + 0, v0);
      atomicAdd(g + 1, v1);
      atomicAdd(g + 2, v2);
      atomicAdd(g + 3, v3);
    }
  }
}

// ---------------------------------------------------------------------------
// MLP head: out[g] = elu(g_row @ fc1 + b) @ out_w + out_b. One wave per graph.
// ---------------------------------------------------------------------------
__global__ __launch_bounds__(64) void head_mlp(const float* __restrict__ gpool,
                                               const float* __restrict__ fc1_w,
                                               const float* __restrict__ fc1_b,
                                               const float* __restrict__ out_w,
                                               const float* __restrict__ out_b,
                                               float* __restrict__ out) {
  int gr = blockIdx.x;
  int c = threadIdx.x;
  float acc = fc1_b[c];
  #pragma unroll 8
  for (int k = 0; k < HIDC; k++)
    acc += gpool[gr * HIDC + k] * fc1_w[k * HIDC + c];
  acc = acc > 0.f ? acc : (__expf(acc) - 1.f);
  float v = acc * out_w[c];
  #pragma unroll
  for (int off = 32; off > 0; off >>= 1) v += __shfl_xor(v, off, 64);
  if (c == 0) out[gr] = v + out_b[0];
}

// ---------------------------------------------------------------------------
// Host launch
// ---------------------------------------------------------------------------
extern "C" void kernel_launch(void* const* d_in, const int* in_sizes, int n_in,
                              void* d_out, int out_size, void* d_ws, size_t ws_size,
                              hipStream_t stream) {
  const float* x      = (const float*)d_in[0];
  const int*   ei     = (const int*)d_in[1];
  const float* eattr  = (const float*)d_in[2];
  const int*   batch  = (const int*)d_in[3];
  const float* w_src1 = (const float*)d_in[4];
  const float* w_dst1 = (const float*)d_in[5];
  const float* w_edge1= (const float*)d_in[6];
  const float* att1   = (const float*)d_in[7];
  const float* b1     = (const float*)d_in[8];
  const float* w_src2 = (const float*)d_in[9];
  const float* w_dst2 = (const float*)d_in[10];
  const float* w_edge2= (const float*)d_in[11];
  const float* att2   = (const float*)d_in[12];
  const float* b2     = (const float*)d_in[13];
  const float* w_src3 = (const float*)d_in[14];
  const float* w_dst3 = (const float*)d_in[15];
  const float* w_edge3= (const float*)d_in[16];
  const float* att3   = (const float*)d_in[17];
  const float* b3     = (const float*)d_in[18];
  const float* fc1_w  = (const float*)d_in[19];
  const float* fc1_b  = (const float*)d_in[20];
  const float* out_w  = (const float*)d_in[21];
  const float* out_b  = (const float*)d_in[22];

  const int* src = ei;
  const int* dst = ei + EE;

  char* p = (char*)d_ws;
  auto carve = [&](size_t bytes) -> void* {
    void* r = (void*)p;
    p += (bytes + 255) & ~(size_t)255;
    return r;
  };
  short* xsd_bf = (short*)carve((size_t)NN * 512 * sizeof(short));  // 51.2 MB bf16 [xs|xd]
  short* xbf1   = (short*)carve((size_t)NN * FF * sizeof(short));   // 12.8 MB
  short* hbf    = (short*)carve((size_t)NN * HC * sizeof(short));   // 25.6 MB
  short* wtcat1 = (short*)carve((size_t)512 * FF * sizeof(short));
  short* wtcat2 = (short*)carve((size_t)512 * HC * sizeof(short));
  short* wtcat3 = (short*)carve((size_t)128 * HC * sizeof(short));
  float* gp     = (float*)carve((size_t)GG * HIDC * sizeof(float));
  int* deg      = (int*)carve((size_t)NN * sizeof(int));
  int* offs     = (int*)carve((size_t)(NN + 1) * sizeof(int));
  int* cur      = (int*)carve((size_t)NN * sizeof(int));
  EPack* pairs  = (EPack*)carve((size_t)(EE + 16) * sizeof(EPack)); // 16 MB
  (void)ws_size; (void)n_in; (void)in_sizes; (void)out_size;

  const int GM128 = (NN + 127) / 128;  // 391

  // --- Prep: zero deg/gp/pairs-tail, cvt x, cvt all weights (ONE dispatch) ---
  WtJobs j;
  j.w[0] = w_src1; j.o[0] = wtcat1;                       j.K[0] = FF; j.N[0] = HC;
  j.w[1] = w_dst1; j.o[1] = wtcat1 + (size_t)HC * FF;     j.K[1] = FF; j.N[1] = HC;
  j.w[2] = w_src2; j.o[2] = wtcat2;                       j.K[2] = HC; j.N[2] = HC;
  j.w[3] = w_dst2; j.o[3] = wtcat2 + (size_t)HC * HC;     j.K[3] = HC; j.N[3] = HC;
  j.w[4] = w_src3; j.o[4] = wtcat3;                       j.K[4] = HC; j.N[4] = HIDC;
  j.w[5] = w_dst3; j.o[5] = wtcat3 + (size_t)HIDC * HC;   j.K[5] = HC; j.N[5] = HIDC;
  j.cum[0] = 0;
  for (int s = 0; s < 6; s++) j.cum[s + 1] = j.cum[s] + j.K[s] * j.N[s];
  prep_all<<<(NN * FF + 255) / 256, 256, 0, stream>>>(x, xbf1, deg, gp,
                                                      (int*)(pairs + EE), j);

  // --- CSR build (shared by all layers) ---
  count_deg<<<(EE + 255) / 256, 256, 0, stream>>>(dst, deg);
  scan_offs<<<1, 1024, 0, stream>>>(deg, offs, cur);
  fill_edges<<<(EE + 255) / 256, 256, 0, stream>>>(src, dst, eattr, cur, pairs);

  // --- Layer 1: one GEMM for [xs|xd] (N=512, K=128) ---
  gemm_bf16_v2<<<dim3(GM128, 4), 256, 0, stream>>>(xbf1, wtcat1, xsd_bf, NN, 512, FF);
  gat_fused4<NHEAD, 512, 0><<<(NN + 3) / 4, HC, 0, stream>>>(xsd_bf, xsd_bf + HC, pairs,
                                                             w_edge1, att1, b1, offs, hbf);

  // --- Layer 2: N=512, K=256 ---
  gemm_bf16_v2<<<dim3(GM128, 4), 256, 0, stream>>>(hbf, wtcat2, xsd_bf, NN, 512, HC);
  gat_fused4<NHEAD, 512, 0><<<(NN + 3) / 4, HC, 0, stream>>>(xsd_bf, xsd_bf + HC, pairs,
                                                             w_edge2, att2, b2, offs, hbf);

  // --- Layer 3: N=128, K=256; fused pool (16 nodes/block, 4 per wave) ---
  gemm_bf16_v2<<<dim3(GM128, 1), 256, 0, stream>>>(hbf, wtcat3, xsd_bf, NN, 128, HC);
  gat_fused_pool4<<<(NN + 15) / 16, 256, 0, stream>>>(xsd_bf, xsd_bf + HIDC, pairs,
                                                      w_edge3, att3, b3, offs, batch, gp);

  // --- MLP head ---
  head_mlp<<<GG, 64, 0, stream>>>(gp, fc1_w, fc1_b, out_w, out_b, (float*)d_out);
}

// Round 12
// 699.151 us; speedup vs baseline: 1.0771x; 1.0134x over previous
//
#include <hip/hip_runtime.h>
#include <hip/hip_bf16.h>
#include <cstddef>
#include <cstdint>

// Problem constants (match reference setup_inputs)
constexpr int NN    = 50000;   // nodes
constexpr int EE    = 500000;  // edges
constexpr int FF    = 128;     // input feature dim
constexpr int HIDC  = 64;      // hidden per head
constexpr int NHEAD = 4;
constexpr int HC    = 256;     // NHEAD * HIDC
constexpr int GG    = 256;     // graphs

typedef __attribute__((ext_vector_type(2))) float f32x2;
typedef __attribute__((ext_vector_type(4))) float f32x4;
typedef __attribute__((ext_vector_type(8))) short bf16x8;

// CSR edge record: src byte-offset (src*1024) + the 6 edge features. 32 B.
struct __align__(16) EPack { int soff; int pad; float e0, e1, e2, e3, e4, e5; };

// round-to-nearest-even fp32 -> bf16 (as short)
__device__ inline short f2bf(float f) {
  union { float f; unsigned u; } v; v.f = f;
  unsigned r = v.u + 0x7fffu + ((v.u >> 16) & 1u);
  return (short)(r >> 16);
}

// unpack 4 bf16 (as uint2) -> two f32x2
__device__ inline void bf4_unpack(uint2 v, f32x2& a, f32x2& b) {
  union { unsigned u; float f; } t;
  t.u = v.x << 16;          a.x = t.f;
  t.u = v.x & 0xffff0000u;  a.y = t.f;
  t.u = v.y << 16;          b.x = t.f;
  t.u = v.y & 0xffff0000u;  b.y = t.f;
}

// ---------------------------------------------------------------------------
// Weight-conversion job table (all 6 matrices)
// ---------------------------------------------------------------------------
struct WtJobs {
  const float* w[6];
  short* o[6];
  int K[6], N[6];
  int cum[7];
};

// ---------------------------------------------------------------------------
// Prep kernel: zero deg + gp + pairs tail, convert x -> bf16, convert all
// weights (transpose+bf16). One dispatch replaces 5.
// ---------------------------------------------------------------------------
__global__ void prep_all(const float* __restrict__ x, short* __restrict__ xbf,
                         int* __restrict__ deg, float* __restrict__ gp,
                         int* __restrict__ pairs_tail, WtJobs j) {
  int i = blockIdx.x * blockDim.x + threadIdx.x;
  if (i < NN * FF) xbf[i] = f2bf(x[i]);
  if (i < NN) deg[i] = 0;
  if (i < GG * HIDC) gp[i] = 0.f;
  if (i < 16 * 8) pairs_tail[i] = 0;           // 16 EPack tail entries
  if (i < j.cum[6]) {
    int s = 0;
    while (i >= j.cum[s + 1]) s++;
    int li = i - j.cum[s];
    int K = j.K[s], N = j.N[s];
    int n = li / K, k = li - n * K;
    j.o[s][li] = f2bf(j.w[s][k * N + n]);
  }
}

// ---------------------------------------------------------------------------
// CSR build (by destination node)
// ---------------------------------------------------------------------------
__global__ void count_deg(const int* __restrict__ dst, int* __restrict__ deg) {
  int i = blockIdx.x * blockDim.x + threadIdx.x;
  if (i < EE) atomicAdd(&deg[dst[i]], 1);
}

__global__ __launch_bounds__(1024) void scan_offs(const int* __restrict__ deg,
                                                  int* __restrict__ offs,
                                                  int* __restrict__ cur) {
  __shared__ int sums[1024];
  int t = threadIdx.x;
  const int chunk = (NN + 1023) / 1024;
  int beg = t * chunk;
  int end = beg + chunk; if (end > NN) end = NN; if (beg > NN) beg = NN;
  int s = 0;
  for (int i = beg; i < end; i++) s += deg[i];
  sums[t] = s;
  __syncthreads();
  for (int off = 1; off < 1024; off <<= 1) {
    int v = (t >= off) ? sums[t - off] : 0;
    __syncthreads();
    sums[t] += v;
    __syncthreads();
  }
  int run = (t == 0) ? 0 : sums[t - 1];
  for (int i = beg; i < end; i++) {
    offs[i] = run; cur[i] = run; run += deg[i];
  }
  if (t == 1023) offs[NN] = run;
}

__global__ void fill_edges(const int* __restrict__ src, const int* __restrict__ dst,
                           const float* __restrict__ eattr,
                           int* __restrict__ cur, EPack* __restrict__ pairs) {
  int i = blockIdx.x * blockDim.x + threadIdx.x;
  if (i < EE) {
    int pos = atomicAdd(&cur[dst[i]], 1);
    const float* ea = eattr + i * 6;
    int4* q = (int4*)(pairs + pos);
    int4 w0, w1;
    w0.x = src[i] * 1024; w0.y = 0;
    w0.z = __float_as_int(ea[0]); w0.w = __float_as_int(ea[1]);
    w1.x = __float_as_int(ea[2]); w1.y = __float_as_int(ea[3]);
    w1.z = __float_as_int(ea[4]); w1.w = __float_as_int(ea[5]);
    q[0] = w0; q[1] = w1;
  }
}

// ---------------------------------------------------------------------------
// bf16 MFMA GEMM, 128x128 tile, BK=64, 256 threads (2x2 waves of 64x64).
// B fragments direct from global (L2-resident weights); LDS only for A.
// (R8-proven: 1564-block grid for N=512 — do not shrink the grid.)
// ---------------------------------------------------------------------------
#define APAD 72

__global__ __launch_bounds__(256) void gemm_bf16_v2(
    const short* __restrict__ A,   // [M][K] bf16
    const short* __restrict__ Bt,  // [N][K] bf16 (transposed weights)
    short* __restrict__ Cbf,       // [M][N] bf16
    int M, int N, int K) {
  __shared__ short As[128][APAD];
  const int tid  = threadIdx.x;
  const int wave = tid >> 6;
  const int lane = tid & 63;
  const int quad = lane >> 4;
  const int l16  = lane & 15;
  const int wr   = wave >> 1;
  const int wc   = wave & 1;
  const int bm = blockIdx.x * 128;
  const int bn = blockIdx.y * 128;

  const int srow = tid >> 3;
  const int skc  = (tid & 7) * 8;

  const short* Bw = Bt + (size_t)(bn + wc * 64 + l16) * K + quad * 8;

  f32x4 acc[4][4];
  #pragma unroll
  for (int i = 0; i < 4; i++)
    #pragma unroll
    for (int jj = 0; jj < 4; jj++) acc[i][jj] = (f32x4){0, 0, 0, 0};

  for (int k0 = 0; k0 < K; k0 += 64) {
    #pragma unroll
    for (int i = 0; i < 4; i++) {
      int r = srow + i * 32;
      int gm = bm + r;
      int4 av = {0, 0, 0, 0};
      if (gm < M) av = *(const int4*)(A + (size_t)gm * K + k0 + skc);
      *(int4*)(&As[r][skc]) = av;
    }
    __syncthreads();

    #pragma unroll
    for (int kq = 0; kq < 2; kq++) {
      bf16x8 bfr[4];
      #pragma unroll
      for (int ni = 0; ni < 4; ni++)
        bfr[ni] = *(const bf16x8*)(Bw + (size_t)(ni * 16) * K + k0 + kq * 32);
      bf16x8 af[4];
      #pragma unroll
      for (int mi = 0; mi < 4; mi++)
        af[mi] = *(const bf16x8*)(&As[wr * 64 + mi * 16 + l16][kq * 32 + quad * 8]);
      #pragma unroll
      for (int mi = 0; mi < 4; mi++)
        #pragma unroll
        for (int ni = 0; ni < 4; ni++)
          acc[mi][ni] = __builtin_amdgcn_mfma_f32_16x16x32_bf16(af[mi], bfr[ni], acc[mi][ni], 0, 0, 0);
    }
    __syncthreads();
  }

  #pragma unroll
  for (int mi = 0; mi < 4; mi++) {
    #pragma unroll
    for (int r = 0; r < 4; r++) {
      int gm = bm + wr * 64 + mi * 16 + quad * 4 + r;
      if (gm < M) {
        #pragma unroll
        for (int ni = 0; ni < 4; ni++)
          Cbf[(size_t)gm * N + bn + wc * 64 + ni * 16 + l16] = f2bf(acc[mi][ni][r]);
      }
    }
  }
}

// ---------------------------------------------------------------------------
// Fused GATv2 edge phase. wave = head; 4 edge-slots x 16 lanes x 4 channels.
// Per iteration: 2x dwordx4 EPack load (src offset + edge feats, ONE address
// stream) + 1 xs bf16x4 gather. No clamp (pairs padded +16 zero entries).
// 2 nodes per wave (R8-proven: 4/wave costs occupancy + tail balance).
// Packed-fp32 math; max-free softmax (logits O(1)). Output bf16.
// ---------------------------------------------------------------------------
template <int H, int CHS, int SOFF_SHR>
__global__ __launch_bounds__(H * 64) void gat_fused4(
    const short* __restrict__ xs, const short* __restrict__ xd,
    const EPack* __restrict__ pairs, const float* __restrict__ w_edge,
    const float* __restrict__ att, const float* __restrict__ bias,
    const int* __restrict__ offs, short* __restrict__ out_bf) {
  constexpr int CH = H * 64;
  const int tid  = threadIdx.x;
  const int head = tid >> 6;
  const int lane = tid & 63;
  const int slot = lane >> 4;
  const int pos  = lane & 15;
  const int ch   = head * 64 + pos * 4;

  const f32x4 attf = *(const f32x4*)(att + ch);
  f32x4 wef[6];
  #pragma unroll
  for (int k = 0; k < 6; k++) wef[k] = *(const f32x4*)(w_edge + k * CH + ch);
  const f32x4 b4 = *(const f32x4*)(bias + ch);

  const char* xs_b = (const char*)xs + ch * 2;

  #pragma unroll
  for (int nn = 0; nn < 2; nn++) {
    const int n = blockIdx.x * 2 + nn;
    if (n >= NN) break;

    uint2 xdr = *(const uint2*)(xd + (size_t)n * CHS + ch);
    f32x2 xd01, xd23; bf4_unpack(xdr, xd01, xd23);

    const int beg = offs[n], end = offs[n + 1];
    float l = 0.f;
    f32x2 acc01 = {0, 0}, acc23 = {0, 0};

    if (beg < end) {
      const int niter = (end - beg + 3) >> 2;
      int idx = beg + slot;
      bool v = idx < end;
      // prefetch (padded array: no clamp needed)
      const int4* pp = (const int4*)(pairs + idx);
      int4 a = pp[0], b = pp[1];
      uint2 xr = *(const uint2*)(xs_b + ((unsigned)a.x >> SOFF_SHR));

      for (int it = 0; it < niter; it++) {
        int4 ac = a, bc = b;
        uint2 xrc = xr;
        bool vc = v;
        idx += 4;
        v = idx < end;
        pp = (const int4*)(pairs + idx);
        a = pp[0]; b = pp[1];
        xr = *(const uint2*)(xs_b + ((unsigned)a.x >> SOFF_SHR));

        f32x2 x01, x23; bf4_unpack(xrc, x01, x23);
        f32x2 e01 = {__int_as_float(ac.z), __int_as_float(ac.w)};
        f32x2 e23 = {__int_as_float(bc.x), __int_as_float(bc.y)};
        f32x2 e45 = {__int_as_float(bc.z), __int_as_float(bc.w)};
        f32x2 z01 = x01 + xd01, z23 = x23 + xd23;
        z01 = __builtin_elementwise_fma((f32x2)(e01.x), wef[0].xy, z01);
        z23 = __builtin_elementwise_fma((f32x2)(e01.x), wef[0].zw, z23);
        z01 = __builtin_elementwise_fma((f32x2)(e01.y), wef[1].xy, z01);
        z23 = __builtin_elementwise_fma((f32x2)(e01.y), wef[1].zw, z23);
        z01 = __builtin_elementwise_fma((f32x2)(e23.x), wef[2].xy, z01);
        z23 = __builtin_elementwise_fma((f32x2)(e23.x), wef[2].zw, z23);
        z01 = __builtin_elementwise_fma((f32x2)(e23.y), wef[3].xy, z01);
        z23 = __builtin_elementwise_fma((f32x2)(e23.y), wef[3].zw, z23);
        z01 = __builtin_elementwise_fma((f32x2)(e45.x), wef[4].xy, z01);
        z23 = __builtin_elementwise_fma((f32x2)(e45.x), wef[4].zw, z23);
        z01 = __builtin_elementwise_fma((f32x2)(e45.y), wef[5].xy, z01);
        z23 = __builtin_elementwise_fma((f32x2)(e45.y), wef[5].zw, z23);
        z01 = __builtin_elementwise_max(z01, z01 * 0.2f);
        z23 = __builtin_elementwise_max(z23, z23 * 0.2f);
        f32x2 d = z01 * attf.xy;
        d = __builtin_elementwise_fma(z23, attf.zw, d);
        float p = d.x + d.y;
        #pragma unroll
        for (int off = 1; off < 16; off <<= 1) p += __shfl_xor(p, off, 64);

        float w = vc ? __expf(p) : 0.f;
        l += w;
        acc01 = __builtin_elementwise_fma((f32x2)w, x01, acc01);
        acc23 = __builtin_elementwise_fma((f32x2)w, x23, acc23);
      }
    }

    // merge the 4 slots (plain sums)
    #pragma unroll
    for (int d = 16; d <= 32; d <<= 1) {
      l       += __shfl_xor(l, d, 64);
      acc01.x += __shfl_xor(acc01.x, d, 64);
      acc01.y += __shfl_xor(acc01.y, d, 64);
      acc23.x += __shfl_xor(acc23.x, d, 64);
      acc23.y += __shfl_xor(acc23.y, d, 64);
    }

    if (slot == 0) {
      float inv = 1.f / (l + 1e-16f);
      float v0 = acc01.x * inv + b4.x;
      float v1 = acc01.y * inv + b4.y;
      float v2 = acc23.x * inv + b4.z;
      float v3 = acc23.y * inv + b4.w;
      v0 = v0 > 0.f ? v0 : (__expf(v0) - 1.f);
      v1 = v1 > 0.f ? v1 : (__expf(v1) - 1.f);
      v2 = v2 > 0.f ? v2 : (__expf(v2) - 1.f);
      v3 = v3 > 0.f ? v3 : (__expf(v3) - 1.f);
      short4 o;
      o.x = f2bf(v0); o.y = f2bf(v1); o.z = f2bf(v2); o.w = f2bf(v3);
      *(short4*)(out_bf + (size_t)n * CH + ch) = o;
    }
  }
}

// Layer-3 + pool variant (H=1, CHS=128, soff>>2): wave = node, 4 nodes per
// wave, 4 waves per block. global_add_pool fused via fp32 atomics.
__global__ __launch_bounds__(256) void gat_fused_pool4(
    const short* __restrict__ xs, const short* __restrict__ xd,
    const EPack* __restrict__ pairs, const float* __restrict__ w_edge,
    const float* __restrict__ att, const float* __restrict__ bias,
    const int* __restrict__ offs, const int* __restrict__ batch,
    float* __restrict__ gp) {
  constexpr int CHS = 128;
  const int lane = threadIdx.x & 63;
  const int slot = lane >> 4;
  const int pos  = lane & 15;
  const int ch   = pos * 4;
  const int nbase = blockIdx.x * 16 + (threadIdx.x >> 6) * 4;

  const f32x4 attf = *(const f32x4*)(att + ch);
  f32x4 wef[6];
  #pragma unroll
  for (int k = 0; k < 6; k++) wef[k] = *(const f32x4*)(w_edge + k * 64 + ch);
  const f32x4 b4 = *(const f32x4*)(bias + ch);

  const char* xs_b = (const char*)xs + ch * 2;

  #pragma unroll
  for (int nn = 0; nn < 4; nn++) {
    const int n = nbase + nn;
    if (n >= NN) break;

    uint2 xdr = *(const uint2*)(xd + (size_t)n * CHS + ch);
    f32x2 xd01, xd23; bf4_unpack(xdr, xd01, xd23);

    const int beg = offs[n], end = offs[n + 1];
    float l = 0.f;
    f32x2 acc01 = {0, 0}, acc23 = {0, 0};

    if (beg < end) {
      const int niter = (end - beg + 3) >> 2;
      int idx = beg + slot;
      bool v = idx < end;
      const int4* pp = (const int4*)(pairs + idx);
      int4 a = pp[0], b = pp[1];
      uint2 xr = *(const uint2*)(xs_b + ((unsigned)a.x >> 2));

      for (int it = 0; it < niter; it++) {
        int4 ac = a, bc = b;
        uint2 xrc = xr;
        bool vc = v;
        idx += 4;
        v = idx < end;
        pp = (const int4*)(pairs + idx);
        a = pp[0]; b = pp[1];
        xr = *(const uint2*)(xs_b + ((unsigned)a.x >> 2));

        f32x2 x01, x23; bf4_unpack(xrc, x01, x23);
        f32x2 e01 = {__int_as_float(ac.z), __int_as_float(ac.w)};
        f32x2 e23 = {__int_as_float(bc.x), __int_as_float(bc.y)};
        f32x2 e45 = {__int_as_float(bc.z), __int_as_float(bc.w)};
        f32x2 z01 = x01 + xd01, z23 = x23 + xd23;
        z01 = __builtin_elementwise_fma((f32x2)(e01.x), wef[0].xy, z01);
        z23 = __builtin_elementwise_fma((f32x2)(e01.x), wef[0].zw, z23);
        z01 = __builtin_elementwise_fma((f32x2)(e01.y), wef[1].xy, z01);
        z23 = __builtin_elementwise_fma((f32x2)(e01.y), wef[1].zw, z23);
        z01 = __builtin_elementwise_fma((f32x2)(e23.x), wef[2].xy, z01);
        z23 = __builtin_elementwise_fma((f32x2)(e23.x), wef[2].zw, z23);
        z01 = __builtin_elementwise_fma((f32x2)(e23.y), wef[3].xy, z01);
        z23 = __builtin_elementwise_fma((f32x2)(e23.y), wef[3].zw, z23);
        z01 = __builtin_elementwise_fma((f32x2)(e45.x), wef[4].xy, z01);
        z23 = __builtin_elementwise_fma((f32x2)(e45.x), wef[4].zw, z23);
        z01 = __builtin_elementwise_fma((f32x2)(e45.y), wef[5].xy, z01);
        z23 = __builtin_elementwise_fma((f32x2)(e45.y), wef[5].zw, z23);
        z01 = __builtin_elementwise_max(z01, z01 * 0.2f);
        z23 = __builtin_elementwise_max(z23, z23 * 0.2f);
        f32x2 d = z01 * attf.xy;
        d = __builtin_elementwise_fma(z23, attf.zw, d);
        float p = d.x + d.y;
        #pragma unroll
        for (int off = 1; off < 16; off <<= 1) p += __shfl_xor(p, off, 64);

        float w = vc ? __expf(p) : 0.f;
        l += w;
        acc01 = __builtin_elementwise_fma((f32x2)w, x01, acc01);
        acc23 = __builtin_elementwise_fma((f32x2)w, x23, acc23);
      }
    }

    #pragma unroll
    for (int d = 16; d <= 32; d <<= 1) {
      l       += __shfl_xor(l, d, 64);
      acc01.x += __shfl_xor(acc01.x, d, 64);
      acc01.y += __shfl_xor(acc01.y, d, 64);
      acc23.x += __shfl_xor(acc23.x, d, 64);
      acc23.y += __shfl_xor(acc23.y, d, 64);
    }

    if (slot == 0) {
      float inv = 1.f / (l + 1e-16f);
      float v0 = acc01.x * inv + b4.x;
      float v1 = acc01.y * inv + b4.y;
      float v2 = acc23.x * inv + b4.z;
      float v3 = acc23.y * inv + b4.w;
      v0 = v0 > 0.f ? v0 : (__expf(v0) - 1.f);
      v1 = v1 > 0.f ? v1 : (__expf(v1) - 1.f);
      v2 = v2 > 0.f ? v2 : (__expf(v2) - 1.f);
      v3 = v3 > 0.f ? v3 : (__expf(v3) - 1.f);
      float* g = gp + (size_t)batch[n] * 64 + ch;
      atomicAdd(g + 0, v0);
      atomicAdd(g + 1, v1);
      atomicAdd(g + 2, v2);
      atomicAdd(g + 3, v3);
    }
  }
}

// ---------------------------------------------------------------------------
// MLP head: out[g] = elu(g_row @ fc1 + b) @ out_w + out_b. One wave per graph.
// ---------------------------------------------------------------------------
__global__ __launch_bounds__(64) void head_mlp(const float* __restrict__ gpool,
                                               const float* __restrict__ fc1_w,
                                               const float* __restrict__ fc1_b,
                                               const float* __restrict__ out_w,
                                               const float* __restrict__ out_b,
                                               float* __restrict__ out) {
  int gr = blockIdx.x;
  int c = threadIdx.x;
  float acc = fc1_b[c];
  #pragma unroll 8
  for (int k = 0; k < HIDC; k++)
    acc += gpool[gr * HIDC + k] * fc1_w[k * HIDC + c];
  acc = acc > 0.f ? acc : (__expf(acc) - 1.f);
  float v = acc * out_w[c];
  #pragma unroll
  for (int off = 32; off > 0; off >>= 1) v += __shfl_xor(v, off, 64);
  if (c == 0) out[gr] = v + out_b[0];
}

// ---------------------------------------------------------------------------
// Host launch
// ---------------------------------------------------------------------------
extern "C" void kernel_launch(void* const* d_in, const int* in_sizes, int n_in,
                              void* d_out, int out_size, void* d_ws, size_t ws_size,
                              hipStream_t stream) {
  const float* x      = (const float*)d_in[0];
  const int*   ei     = (const int*)d_in[1];
  const float* eattr  = (const float*)d_in[2];
  const int*   batch  = (const int*)d_in[3];
  const float* w_src1 = (const float*)d_in[4];
  const float* w_dst1 = (const float*)d_in[5];
  const float* w_edge1= (const float*)d_in[6];
  const float* att1   = (const float*)d_in[7];
  const float* b1     = (const float*)d_in[8];
  const float* w_src2 = (const float*)d_in[9];
  const float* w_dst2 = (const float*)d_in[10];
  const float* w_edge2= (const float*)d_in[11];
  const float* att2   = (const float*)d_in[12];
  const float* b2     = (const float*)d_in[13];
  const float* w_src3 = (const float*)d_in[14];
  const float* w_dst3 = (const float*)d_in[15];
  const float* w_edge3= (const float*)d_in[16];
  const float* att3   = (const float*)d_in[17];
  const float* b3     = (const float*)d_in[18];
  const float* fc1_w  = (const float*)d_in[19];
  const float* fc1_b  = (const float*)d_in[20];
  const float* out_w  = (const float*)d_in[21];
  const float* out_b  = (const float*)d_in[22];

  const int* src = ei;
  const int* dst = ei + EE;

  char* p = (char*)d_ws;
  auto carve = [&](size_t bytes) -> void* {
    void* r = (void*)p;
    p += (bytes + 255) & ~(size_t)255;
    return r;
  };
  short* xsd_bf = (short*)carve((size_t)NN * 512 * sizeof(short));  // 51.2 MB bf16 [xs|xd]
  short* xbf1   = (short*)carve((size_t)NN * FF * sizeof(short));   // 12.8 MB
  short* hbf    = (short*)carve((size_t)NN * HC * sizeof(short));   // 25.6 MB
  short* wtcat1 = (short*)carve((size_t)512 * FF * sizeof(short));
  short* wtcat2 = (short*)carve((size_t)512 * HC * sizeof(short));
  short* wtcat3 = (short*)carve((size_t)128 * HC * sizeof(short));
  float* gp     = (float*)carve((size_t)GG * HIDC * sizeof(float));
  int* deg      = (int*)carve((size_t)NN * sizeof(int));
  int* offs     = (int*)carve((size_t)(NN + 1) * sizeof(int));
  int* cur      = (int*)carve((size_t)NN * sizeof(int));
  EPack* pairs  = (EPack*)carve((size_t)(EE + 16) * sizeof(EPack)); // 16 MB
  (void)ws_size; (void)n_in; (void)in_sizes; (void)out_size;

  const int GM128 = (NN + 127) / 128;  // 391

  // --- Prep: zero deg/gp/pairs-tail, cvt x, cvt all weights (ONE dispatch) ---
  WtJobs j;
  j.w[0] = w_src1; j.o[0] = wtcat1;                       j.K[0] = FF; j.N[0] = HC;
  j.w[1] = w_dst1; j.o[1] = wtcat1 + (size_t)HC * FF;     j.K[1] = FF; j.N[1] = HC;
  j.w[2] = w_src2; j.o[2] = wtcat2;                       j.K[2] = HC; j.N[2] = HC;
  j.w[3] = w_dst2; j.o[3] = wtcat2 + (size_t)HC * HC;     j.K[3] = HC; j.N[3] = HC;
  j.w[4] = w_src3; j.o[4] = wtcat3;                       j.K[4] = HC; j.N[4] = HIDC;
  j.w[5] = w_dst3; j.o[5] = wtcat3 + (size_t)HIDC * HC;   j.K[5] = HC; j.N[5] = HIDC;
  j.cum[0] = 0;
  for (int s = 0; s < 6; s++) j.cum[s + 1] = j.cum[s] + j.K[s] * j.N[s];
  prep_all<<<(NN * FF + 255) / 256, 256, 0, stream>>>(x, xbf1, deg, gp,
                                                      (int*)(pairs + EE), j);

  // --- CSR build (shared by all layers) ---
  count_deg<<<(EE + 255) / 256, 256, 0, stream>>>(dst, deg);
  scan_offs<<<1, 1024, 0, stream>>>(deg, offs, cur);
  fill_edges<<<(EE + 255) / 256, 256, 0, stream>>>(src, dst, eattr, cur, pairs);

  // --- Layer 1: one GEMM for [xs|xd] (N=512, K=128) ---
  gemm_bf16_v2<<<dim3(GM128, 4), 256, 0, stream>>>(xbf1, wtcat1, xsd_bf, NN, 512, FF);
  gat_fused4<NHEAD, 512, 0><<<(NN + 1) / 2, HC, 0, stream>>>(xsd_bf, xsd_bf + HC, pairs,
                                                             w_edge1, att1, b1, offs, hbf);

  // --- Layer 2: N=512, K=256 ---
  gemm_bf16_v2<<<dim3(GM128, 4), 256, 0, stream>>>(hbf, wtcat2, xsd_bf, NN, 512, HC);
  gat_fused4<NHEAD, 512, 0><<<(NN + 1) / 2, HC, 0, stream>>>(xsd_bf, xsd_bf + HC, pairs,
                                                             w_edge2, att2, b2, offs, hbf);

  // --- Layer 3: N=128, K=256; fused pool (16 nodes/block, 4 per wave) ---
  gemm_bf16_v2<<<dim3(GM128, 1), 256, 0, stream>>>(hbf, wtcat3, xsd_bf, NN, 128, HC);
  gat_fused_pool4<<<(NN + 15) / 16, 256, 0, stream>>>(xsd_bf, xsd_bf + HIDC, pairs,
                                                      w_edge3, att3, b3, offs, batch, gp);

  // --- MLP head ---
  head_mlp<<<GG, 64, 0, stream>>>(gp, fc1_w, fc1_b, out_w, out_b, (float*)d_out);
}

// Round 13
// 587.440 us; speedup vs baseline: 1.2819x; 1.1902x over previous
//
#include <hip/hip_runtime.h>
#include <hip/hip_bf16.h>
#include <cstddef>
#include <cstdint>

// Problem constants (match reference setup_inputs)
constexpr int NN    = 50000;   // nodes
constexpr int EE    = 500000;  // edges
constexpr int FF    = 128;     // input feature dim
constexpr int HIDC  = 64;      // hidden per head
constexpr int NHEAD = 4;
constexpr int HC    = 256;     // NHEAD * HIDC
constexpr int GG    = 256;     // graphs

typedef __attribute__((ext_vector_type(2))) float f32x2;
typedef __attribute__((ext_vector_type(4))) float f32x4;
typedef __attribute__((ext_vector_type(8))) short bf16x8;

// CSR edge record: src byte-offset (src*1024) + the 6 edge features. 32 B.
struct __align__(16) EPack { int soff; int pad; float e0, e1, e2, e3, e4, e5; };

// round-to-nearest-even fp32 -> bf16 (as short)
__device__ inline short f2bf(float f) {
  union { float f; unsigned u; } v; v.f = f;
  unsigned r = v.u + 0x7fffu + ((v.u >> 16) & 1u);
  return (short)(r >> 16);
}

// unpack 4 bf16 (as uint2) -> two f32x2
__device__ inline void bf4_unpack(uint2 v, f32x2& a, f32x2& b) {
  union { unsigned u; float f; } t;
  t.u = v.x << 16;          a.x = t.f;
  t.u = v.x & 0xffff0000u;  a.y = t.f;
  t.u = v.y << 16;          b.x = t.f;
  t.u = v.y & 0xffff0000u;  b.y = t.f;
}

// ---------------------------------------------------------------------------
// Weight-conversion job table (all 6 matrices)
// ---------------------------------------------------------------------------
struct WtJobs {
  const float* w[6];
  short* o[6];
  int K[6], N[6];
  int cum[7];
};

// ---------------------------------------------------------------------------
// Prep kernel: zero deg + gp + pairs tail, convert x -> bf16, convert all
// weights (transpose+bf16). One dispatch replaces 5.
// ---------------------------------------------------------------------------
__global__ void prep_all(const float* __restrict__ x, short* __restrict__ xbf,
                         int* __restrict__ deg, float* __restrict__ gp,
                         int* __restrict__ pairs_tail, WtJobs j) {
  int i = blockIdx.x * blockDim.x + threadIdx.x;
  if (i < NN * FF) xbf[i] = f2bf(x[i]);
  if (i < NN) deg[i] = 0;
  if (i < GG * HIDC) gp[i] = 0.f;
  if (i < 16 * 8) pairs_tail[i] = 0;           // 16 EPack tail entries
  if (i < j.cum[6]) {
    int s = 0;
    while (i >= j.cum[s + 1]) s++;
    int li = i - j.cum[s];
    int K = j.K[s], N = j.N[s];
    int n = li / K, k = li - n * K;
    j.o[s][li] = f2bf(j.w[s][k * N + n]);
  }
}

// ---------------------------------------------------------------------------
// CSR build (by destination node). Parallel 3-stage scan replaces the old
// single-block (single-CU!) scan_offs.
// ---------------------------------------------------------------------------
__global__ void count_deg(const int* __restrict__ dst, int* __restrict__ deg) {
  int i = blockIdx.x * blockDim.x + threadIdx.x;
  if (i < EE) atomicAdd(&deg[dst[i]], 1);
}

constexpr int SCAN_T = 256;   // threads per scan block
constexpr int SCAN_B = 64;    // scan blocks
constexpr int SCHUNK = 4;     // elems per thread (64*256*4 = 65536 >= NN)

// Stage 1: per-block sums of deg
__global__ __launch_bounds__(SCAN_T) void scan_stage1(const int* __restrict__ deg,
                                                      int* __restrict__ bsum) {
  __shared__ int red[SCAN_T];
  const int t = threadIdx.x, b = blockIdx.x;
  int base = (b * SCAN_T + t) * SCHUNK;
  int s = 0;
  #pragma unroll
  for (int i = 0; i < SCHUNK; i++) {
    int idx = base + i;
    if (idx < NN) s += deg[idx];
  }
  red[t] = s;
  __syncthreads();
  for (int off = SCAN_T / 2; off > 0; off >>= 1) {
    if (t < off) red[t] += red[t + off];
    __syncthreads();
  }
  if (t == 0) bsum[b] = red[0];
}

// Stage 2: inclusive scan of the 64 block sums (one wave)
__global__ __launch_bounds__(64) void scan_stage2(int* __restrict__ bsum) {
  int t = threadIdx.x;
  int v = bsum[t];
  #pragma unroll
  for (int off = 1; off < 64; off <<= 1) {
    int o = __shfl_up(v, off, 64);
    if (t >= off) v += o;
  }
  bsum[t] = v;   // inclusive
}

// Stage 3: full exclusive prefix -> offs/cur (+ offs[NN] = total)
__global__ __launch_bounds__(SCAN_T) void scan_stage3(const int* __restrict__ deg,
                                                      const int* __restrict__ bsum,
                                                      int* __restrict__ offs,
                                                      int* __restrict__ cur) {
  __shared__ int red[SCAN_T];
  const int t = threadIdx.x, b = blockIdx.x;
  const int base = (b * SCAN_T + t) * SCHUNK;
  int local[SCHUNK];
  int s = 0;
  #pragma unroll
  for (int i = 0; i < SCHUNK; i++) {
    int idx = base + i;
    local[i] = (idx < NN) ? deg[idx] : 0;
    s += local[i];
  }
  red[t] = s;
  __syncthreads();
  for (int off = 1; off < SCAN_T; off <<= 1) {   // Hillis-Steele inclusive
    int v = (t >= off) ? red[t - off] : 0;
    __syncthreads();
    red[t] += v;
    __syncthreads();
  }
  const int blockBase = (b == 0) ? 0 : bsum[b - 1];
  int run = blockBase + red[t] - s;              // exclusive prefix for this thread
  #pragma unroll
  for (int i = 0; i < SCHUNK; i++) {
    int idx = base + i;
    if (idx < NN) {
      offs[idx] = run; cur[idx] = run; run += local[i];
    }
  }
  if (b == SCAN_B - 1 && t == SCAN_T - 1) offs[NN] = run;  // == EE
}

__global__ void fill_edges(const int* __restrict__ src, const int* __restrict__ dst,
                           const float* __restrict__ eattr,
                           int* __restrict__ cur, EPack* __restrict__ pairs) {
  int i = blockIdx.x * blockDim.x + threadIdx.x;
  if (i < EE) {
    int pos = atomicAdd(&cur[dst[i]], 1);
    const float* ea = eattr + i * 6;
    int4* q = (int4*)(pairs + pos);
    int4 w0, w1;
    w0.x = src[i] * 1024; w0.y = 0;
    w0.z = __float_as_int(ea[0]); w0.w = __float_as_int(ea[1]);
    w1.x = __float_as_int(ea[2]); w1.y = __float_as_int(ea[3]);
    w1.z = __float_as_int(ea[4]); w1.w = __float_as_int(ea[5]);
    q[0] = w0; q[1] = w1;
  }
}

// ---------------------------------------------------------------------------
// bf16 MFMA GEMM, 128x128 tile, BK=64, 256 threads (2x2 waves of 64x64).
// B fragments direct from global (L2-resident weights); LDS only for A.
// (R8-proven: 1564-block grid for N=512 — do not shrink the grid.)
// ---------------------------------------------------------------------------
#define APAD 72

__global__ __launch_bounds__(256) void gemm_bf16_v2(
    const short* __restrict__ A,   // [M][K] bf16
    const short* __restrict__ Bt,  // [N][K] bf16 (transposed weights)
    short* __restrict__ Cbf,       // [M][N] bf16
    int M, int N, int K) {
  __shared__ short As[128][APAD];
  const int tid  = threadIdx.x;
  const int wave = tid >> 6;
  const int lane = tid & 63;
  const int quad = lane >> 4;
  const int l16  = lane & 15;
  const int wr   = wave >> 1;
  const int wc   = wave & 1;
  const int bm = blockIdx.x * 128;
  const int bn = blockIdx.y * 128;

  const int srow = tid >> 3;
  const int skc  = (tid & 7) * 8;

  const short* Bw = Bt + (size_t)(bn + wc * 64 + l16) * K + quad * 8;

  f32x4 acc[4][4];
  #pragma unroll
  for (int i = 0; i < 4; i++)
    #pragma unroll
    for (int jj = 0; jj < 4; jj++) acc[i][jj] = (f32x4){0, 0, 0, 0};

  for (int k0 = 0; k0 < K; k0 += 64) {
    #pragma unroll
    for (int i = 0; i < 4; i++) {
      int r = srow + i * 32;
      int gm = bm + r;
      int4 av = {0, 0, 0, 0};
      if (gm < M) av = *(const int4*)(A + (size_t)gm * K + k0 + skc);
      *(int4*)(&As[r][skc]) = av;
    }
    __syncthreads();

    #pragma unroll
    for (int kq = 0; kq < 2; kq++) {
      bf16x8 bfr[4];
      #pragma unroll
      for (int ni = 0; ni < 4; ni++)
        bfr[ni] = *(const bf16x8*)(Bw + (size_t)(ni * 16) * K + k0 + kq * 32);
      bf16x8 af[4];
      #pragma unroll
      for (int mi = 0; mi < 4; mi++)
        af[mi] = *(const bf16x8*)(&As[wr * 64 + mi * 16 + l16][kq * 32 + quad * 8]);
      #pragma unroll
      for (int mi = 0; mi < 4; mi++)
        #pragma unroll
        for (int ni = 0; ni < 4; ni++)
          acc[mi][ni] = __builtin_amdgcn_mfma_f32_16x16x32_bf16(af[mi], bfr[ni], acc[mi][ni], 0, 0, 0);
    }
    __syncthreads();
  }

  #pragma unroll
  for (int mi = 0; mi < 4; mi++) {
    #pragma unroll
    for (int r = 0; r < 4; r++) {
      int gm = bm + wr * 64 + mi * 16 + quad * 4 + r;
      if (gm < M) {
        #pragma unroll
        for (int ni = 0; ni < 4; ni++)
          Cbf[(size_t)gm * N + bn + wc * 64 + ni * 16 + l16] = f2bf(acc[mi][ni][r]);
      }
    }
  }
}

// ---------------------------------------------------------------------------
// Fused GATv2 edge phase. wave = head; 4 edge-slots x 16 lanes x 4 channels.
// Per iteration: 2x dwordx4 EPack load (src offset + edge feats, ONE address
// stream) + 1 xs bf16x4 gather. No clamp (pairs padded +16 zero entries).
// 2 nodes per wave (R8-proven). Packed-fp32 math; max-free softmax
// (logits O(1)). Output bf16.
// ---------------------------------------------------------------------------
template <int H, int CHS, int SOFF_SHR>
__global__ __launch_bounds__(H * 64) void gat_fused4(
    const short* __restrict__ xs, const short* __restrict__ xd,
    const EPack* __restrict__ pairs, const float* __restrict__ w_edge,
    const float* __restrict__ att, const float* __restrict__ bias,
    const int* __restrict__ offs, short* __restrict__ out_bf) {
  constexpr int CH = H * 64;
  const int tid  = threadIdx.x;
  const int head = tid >> 6;
  const int lane = tid & 63;
  const int slot = lane >> 4;
  const int pos  = lane & 15;
  const int ch   = head * 64 + pos * 4;

  const f32x4 attf = *(const f32x4*)(att + ch);
  f32x4 wef[6];
  #pragma unroll
  for (int k = 0; k < 6; k++) wef[k] = *(const f32x4*)(w_edge + k * CH + ch);
  const f32x4 b4 = *(const f32x4*)(bias + ch);

  const char* xs_b = (const char*)xs + ch * 2;

  #pragma unroll
  for (int nn = 0; nn < 2; nn++) {
    const int n = blockIdx.x * 2 + nn;
    if (n >= NN) break;

    uint2 xdr = *(const uint2*)(xd + (size_t)n * CHS + ch);
    f32x2 xd01, xd23; bf4_unpack(xdr, xd01, xd23);

    const int beg = offs[n], end = offs[n + 1];
    float l = 0.f;
    f32x2 acc01 = {0, 0}, acc23 = {0, 0};

    if (beg < end) {
      const int niter = (end - beg + 3) >> 2;
      int idx = beg + slot;
      bool v = idx < end;
      // prefetch (padded array: no clamp needed)
      const int4* pp = (const int4*)(pairs + idx);
      int4 a = pp[0], b = pp[1];
      uint2 xr = *(const uint2*)(xs_b + ((unsigned)a.x >> SOFF_SHR));

      for (int it = 0; it < niter; it++) {
        int4 ac = a, bc = b;
        uint2 xrc = xr;
        bool vc = v;
        idx += 4;
        v = idx < end;
        pp = (const int4*)(pairs + idx);
        a = pp[0]; b = pp[1];
        xr = *(const uint2*)(xs_b + ((unsigned)a.x >> SOFF_SHR));

        f32x2 x01, x23; bf4_unpack(xrc, x01, x23);
        f32x2 e01 = {__int_as_float(ac.z), __int_as_float(ac.w)};
        f32x2 e23 = {__int_as_float(bc.x), __int_as_float(bc.y)};
        f32x2 e45 = {__int_as_float(bc.z), __int_as_float(bc.w)};
        f32x2 z01 = x01 + xd01, z23 = x23 + xd23;
        z01 = __builtin_elementwise_fma((f32x2)(e01.x), wef[0].xy, z01);
        z23 = __builtin_elementwise_fma((f32x2)(e01.x), wef[0].zw, z23);
        z01 = __builtin_elementwise_fma((f32x2)(e01.y), wef[1].xy, z01);
        z23 = __builtin_elementwise_fma((f32x2)(e01.y), wef[1].zw, z23);
        z01 = __builtin_elementwise_fma((f32x2)(e23.x), wef[2].xy, z01);
        z23 = __builtin_elementwise_fma((f32x2)(e23.x), wef[2].zw, z23);
        z01 = __builtin_elementwise_fma((f32x2)(e23.y), wef[3].xy, z01);
        z23 = __builtin_elementwise_fma((f32x2)(e23.y), wef[3].zw, z23);
        z01 = __builtin_elementwise_fma((f32x2)(e45.x), wef[4].xy, z01);
        z23 = __builtin_elementwise_fma((f32x2)(e45.x), wef[4].zw, z23);
        z01 = __builtin_elementwise_fma((f32x2)(e45.y), wef[5].xy, z01);
        z23 = __builtin_elementwise_fma((f32x2)(e45.y), wef[5].zw, z23);
        z01 = __builtin_elementwise_max(z01, z01 * 0.2f);
        z23 = __builtin_elementwise_max(z23, z23 * 0.2f);
        f32x2 d = z01 * attf.xy;
        d = __builtin_elementwise_fma(z23, attf.zw, d);
        float p = d.x + d.y;
        #pragma unroll
        for (int off = 1; off < 16; off <<= 1) p += __shfl_xor(p, off, 64);

        float w = vc ? __expf(p) : 0.f;
        l += w;
        acc01 = __builtin_elementwise_fma((f32x2)w, x01, acc01);
        acc23 = __builtin_elementwise_fma((f32x2)w, x23, acc23);
      }
    }

    // merge the 4 slots (plain sums)
    #pragma unroll
    for (int d = 16; d <= 32; d <<= 1) {
      l       += __shfl_xor(l, d, 64);
      acc01.x += __shfl_xor(acc01.x, d, 64);
      acc01.y += __shfl_xor(acc01.y, d, 64);
      acc23.x += __shfl_xor(acc23.x, d, 64);
      acc23.y += __shfl_xor(acc23.y, d, 64);
    }

    if (slot == 0) {
      float inv = 1.f / (l + 1e-16f);
      float v0 = acc01.x * inv + b4.x;
      float v1 = acc01.y * inv + b4.y;
      float v2 = acc23.x * inv + b4.z;
      float v3 = acc23.y * inv + b4.w;
      v0 = v0 > 0.f ? v0 : (__expf(v0) - 1.f);
      v1 = v1 > 0.f ? v1 : (__expf(v1) - 1.f);
      v2 = v2 > 0.f ? v2 : (__expf(v2) - 1.f);
      v3 = v3 > 0.f ? v3 : (__expf(v3) - 1.f);
      short4 o;
      o.x = f2bf(v0); o.y = f2bf(v1); o.z = f2bf(v2); o.w = f2bf(v3);
      *(short4*)(out_bf + (size_t)n * CH + ch) = o;
    }
  }
}

// Layer-3 + pool variant (H=1, CHS=128, soff>>2): wave = node, 4 nodes per
// wave, 4 waves per block. global_add_pool fused via fp32 atomics.
__global__ __launch_bounds__(256) void gat_fused_pool4(
    const short* __restrict__ xs, const short* __restrict__ xd,
    const EPack* __restrict__ pairs, const float* __restrict__ w_edge,
    const float* __restrict__ att, const float* __restrict__ bias,
    const int* __restrict__ offs, const int* __restrict__ batch,
    float* __restrict__ gp) {
  constexpr int CHS = 128;
  const int lane = threadIdx.x & 63;
  const int slot = lane >> 4;
  const int pos  = lane & 15;
  const int ch   = pos * 4;
  const int nbase = blockIdx.x * 16 + (threadIdx.x >> 6) * 4;

  const f32x4 attf = *(const f32x4*)(att + ch);
  f32x4 wef[6];
  #pragma unroll
  for (int k = 0; k < 6; k++) wef[k] = *(const f32x4*)(w_edge + k * 64 + ch);
  const f32x4 b4 = *(const f32x4*)(bias + ch);

  const char* xs_b = (const char*)xs + ch * 2;

  #pragma unroll
  for (int nn = 0; nn < 4; nn++) {
    const int n = nbase + nn;
    if (n >= NN) break;

    uint2 xdr = *(const uint2*)(xd + (size_t)n * CHS + ch);
    f32x2 xd01, xd23; bf4_unpack(xdr, xd01, xd23);

    const int beg = offs[n], end = offs[n + 1];
    float l = 0.f;
    f32x2 acc01 = {0, 0}, acc23 = {0, 0};

    if (beg < end) {
      const int niter = (end - beg + 3) >> 2;
      int idx = beg + slot;
      bool v = idx < end;
      const int4* pp = (const int4*)(pairs + idx);
      int4 a = pp[0], b = pp[1];
      uint2 xr = *(const uint2*)(xs_b + ((unsigned)a.x >> 2));

      for (int it = 0; it < niter; it++) {
        int4 ac = a, bc = b;
        uint2 xrc = xr;
        bool vc = v;
        idx += 4;
        v = idx < end;
        pp = (const int4*)(pairs + idx);
        a = pp[0]; b = pp[1];
        xr = *(const uint2*)(xs_b + ((unsigned)a.x >> 2));

        f32x2 x01, x23; bf4_unpack(xrc, x01, x23);
        f32x2 e01 = {__int_as_float(ac.z), __int_as_float(ac.w)};
        f32x2 e23 = {__int_as_float(bc.x), __int_as_float(bc.y)};
        f32x2 e45 = {__int_as_float(bc.z), __int_as_float(bc.w)};
        f32x2 z01 = x01 + xd01, z23 = x23 + xd23;
        z01 = __builtin_elementwise_fma((f32x2)(e01.x), wef[0].xy, z01);
        z23 = __builtin_elementwise_fma((f32x2)(e01.x), wef[0].zw, z23);
        z01 = __builtin_elementwise_fma((f32x2)(e01.y), wef[1].xy, z01);
        z23 = __builtin_elementwise_fma((f32x2)(e01.y), wef[1].zw, z23);
        z01 = __builtin_elementwise_fma((f32x2)(e23.x), wef[2].xy, z01);
        z23 = __builtin_elementwise_fma((f32x2)(e23.x), wef[2].zw, z23);
        z01 = __builtin_elementwise_fma((f32x2)(e23.y), wef[3].xy, z01);
        z23 = __builtin_elementwise_fma((f32x2)(e23.y), wef[3].zw, z23);
        z01 = __builtin_elementwise_fma((f32x2)(e45.x), wef[4].xy, z01);
        z23 = __builtin_elementwise_fma((f32x2)(e45.x), wef[4].zw, z23);
        z01 = __builtin_elementwise_fma((f32x2)(e45.y), wef[5].xy, z01);
        z23 = __builtin_elementwise_fma((f32x2)(e45.y), wef[5].zw, z23);
        z01 = __builtin_elementwise_max(z01, z01 * 0.2f);
        z23 = __builtin_elementwise_max(z23, z23 * 0.2f);
        f32x2 d = z01 * attf.xy;
        d = __builtin_elementwise_fma(z23, attf.zw, d);
        float p = d.x + d.y;
        #pragma unroll
        for (int off = 1; off < 16; off <<= 1) p += __shfl_xor(p, off, 64);

        float w = vc ? __expf(p) : 0.f;
        l += w;
        acc01 = __builtin_elementwise_fma((f32x2)w, x01, acc01);
        acc23 = __builtin_elementwise_fma((f32x2)w, x23, acc23);
      }
    }

    #pragma unroll
    for (int d = 16; d <= 32; d <<= 1) {
      l       += __shfl_xor(l, d, 64);
      acc01.x += __shfl_xor(acc01.x, d, 64);
      acc01.y += __shfl_xor(acc01.y, d, 64);
      acc23.x += __shfl_xor(acc23.x, d, 64);
      acc23.y += __shfl_xor(acc23.y, d, 64);
    }

    if (slot == 0) {
      float inv = 1.f / (l + 1e-16f);
      float v0 = acc01.x * inv + b4.x;
      float v1 = acc01.y * inv + b4.y;
      float v2 = acc23.x * inv + b4.z;
      float v3 = acc23.y * inv + b4.w;
      v0 = v0 > 0.f ? v0 : (__expf(v0) - 1.f);
      v1 = v1 > 0.f ? v1 : (__expf(v1) - 1.f);
      v2 = v2 > 0.f ? v2 : (__expf(v2) - 1.f);
      v3 = v3 > 0.f ? v3 : (__expf(v3) - 1.f);
      float* g = gp + (size_t)batch[n] * 64 + ch;
      atomicAdd(g + 0, v0);
      atomicAdd(g + 1, v1);
      atomicAdd(g + 2, v2);
      atomicAdd(g + 3, v3);
    }
  }
}

// ---------------------------------------------------------------------------
// MLP head: out[g] = elu(g_row @ fc1 + b) @ out_w + out_b. One wave per graph.
// ---------------------------------------------------------------------------
__global__ __launch_bounds__(64) void head_mlp(const float* __restrict__ gpool,
                                               const float* __restrict__ fc1_w,
                                               const float* __restrict__ fc1_b,
                                               const float* __restrict__ out_w,
                                               const float* __restrict__ out_b,
                                               float* __restrict__ out) {
  int gr = blockIdx.x;
  int c = threadIdx.x;
  float acc = fc1_b[c];
  #pragma unroll 8
  for (int k = 0; k < HIDC; k++)
    acc += gpool[gr * HIDC + k] * fc1_w[k * HIDC + c];
  acc = acc > 0.f ? acc : (__expf(acc) - 1.f);
  float v = acc * out_w[c];
  #pragma unroll
  for (int off = 32; off > 0; off >>= 1) v += __shfl_xor(v, off, 64);
  if (c == 0) out[gr] = v + out_b[0];
}

// ---------------------------------------------------------------------------
// Host launch
// ---------------------------------------------------------------------------
extern "C" void kernel_launch(void* const* d_in, const int* in_sizes, int n_in,
                              void* d_out, int out_size, void* d_ws, size_t ws_size,
                              hipStream_t stream) {
  const float* x      = (const float*)d_in[0];
  const int*   ei     = (const int*)d_in[1];
  const float* eattr  = (const float*)d_in[2];
  const int*   batch  = (const int*)d_in[3];
  const float* w_src1 = (const float*)d_in[4];
  const float* w_dst1 = (const float*)d_in[5];
  const float* w_edge1= (const float*)d_in[6];
  const float* att1   = (const float*)d_in[7];
  const float* b1     = (const float*)d_in[8];
  const float* w_src2 = (const float*)d_in[9];
  const float* w_dst2 = (const float*)d_in[10];
  const float* w_edge2= (const float*)d_in[11];
  const float* att2   = (const float*)d_in[12];
  const float* b2     = (const float*)d_in[13];
  const float* w_src3 = (const float*)d_in[14];
  const float* w_dst3 = (const float*)d_in[15];
  const float* w_edge3= (const float*)d_in[16];
  const float* att3   = (const float*)d_in[17];
  const float* b3     = (const float*)d_in[18];
  const float* fc1_w  = (const float*)d_in[19];
  const float* fc1_b  = (const float*)d_in[20];
  const float* out_w  = (const float*)d_in[21];
  const float* out_b  = (const float*)d_in[22];

  const int* src = ei;
  const int* dst = ei + EE;

  char* p = (char*)d_ws;
  auto carve = [&](size_t bytes) -> void* {
    void* r = (void*)p;
    p += (bytes + 255) & ~(size_t)255;
    return r;
  };
  short* xsd_bf = (short*)carve((size_t)NN * 512 * sizeof(short));  // 51.2 MB bf16 [xs|xd]
  short* xbf1   = (short*)carve((size_t)NN * FF * sizeof(short));   // 12.8 MB
  short* hbf    = (short*)carve((size_t)NN * HC * sizeof(short));   // 25.6 MB
  short* wtcat1 = (short*)carve((size_t)512 * FF * sizeof(short));
  short* wtcat2 = (short*)carve((size_t)512 * HC * sizeof(short));
  short* wtcat3 = (short*)carve((size_t)128 * HC * sizeof(short));
  float* gp     = (float*)carve((size_t)GG * HIDC * sizeof(float));
  int* deg      = (int*)carve((size_t)NN * sizeof(int));
  int* offs     = (int*)carve((size_t)(NN + 1) * sizeof(int));
  int* cur      = (int*)carve((size_t)NN * sizeof(int));
  int* bsum     = (int*)carve((size_t)SCAN_B * sizeof(int));
  EPack* pairs  = (EPack*)carve((size_t)(EE + 16) * sizeof(EPack)); // 16 MB
  (void)ws_size; (void)n_in; (void)in_sizes; (void)out_size;

  const int GM128 = (NN + 127) / 128;  // 391

  // --- Prep: zero deg/gp/pairs-tail, cvt x, cvt all weights (ONE dispatch) ---
  WtJobs j;
  j.w[0] = w_src1; j.o[0] = wtcat1;                       j.K[0] = FF; j.N[0] = HC;
  j.w[1] = w_dst1; j.o[1] = wtcat1 + (size_t)HC * FF;     j.K[1] = FF; j.N[1] = HC;
  j.w[2] = w_src2; j.o[2] = wtcat2;                       j.K[2] = HC; j.N[2] = HC;
  j.w[3] = w_dst2; j.o[3] = wtcat2 + (size_t)HC * HC;     j.K[3] = HC; j.N[3] = HC;
  j.w[4] = w_src3; j.o[4] = wtcat3;                       j.K[4] = HC; j.N[4] = HIDC;
  j.w[5] = w_dst3; j.o[5] = wtcat3 + (size_t)HIDC * HC;   j.K[5] = HC; j.N[5] = HIDC;
  j.cum[0] = 0;
  for (int s = 0; s < 6; s++) j.cum[s + 1] = j.cum[s] + j.K[s] * j.N[s];
  prep_all<<<(NN * FF + 255) / 256, 256, 0, stream>>>(x, xbf1, deg, gp,
                                                      (int*)(pairs + EE), j);

  // --- CSR build (shared by all layers); parallel 3-stage scan ---
  count_deg<<<(EE + 255) / 256, 256, 0, stream>>>(dst, deg);
  scan_stage1<<<SCAN_B, SCAN_T, 0, stream>>>(deg, bsum);
  scan_stage2<<<1, 64, 0, stream>>>(bsum);
  scan_stage3<<<SCAN_B, SCAN_T, 0, stream>>>(deg, bsum, offs, cur);
  fill_edges<<<(EE + 255) / 256, 256, 0, stream>>>(src, dst, eattr, cur, pairs);

  // --- Layer 1: one GEMM for [xs|xd] (N=512, K=128) ---
  gemm_bf16_v2<<<dim3(GM128, 4), 256, 0, stream>>>(xbf1, wtcat1, xsd_bf, NN, 512, FF);
  gat_fused4<NHEAD, 512, 0><<<(NN + 1) / 2, HC, 0, stream>>>(xsd_bf, xsd_bf + HC, pairs,
                                                             w_edge1, att1, b1, offs, hbf);

  // --- Layer 2: N=512, K=256 ---
  gemm_bf16_v2<<<dim3(GM128, 4), 256, 0, stream>>>(hbf, wtcat2, xsd_bf, NN, 512, HC);
  gat_fused4<NHEAD, 512, 0><<<(NN + 1) / 2, HC, 0, stream>>>(xsd_bf, xsd_bf + HC, pairs,
                                                             w_edge2, att2, b2, offs, hbf);

  // --- Layer 3: N=128, K=256; fused pool (16 nodes/block, 4 per wave) ---
  gemm_bf16_v2<<<dim3(GM128, 1), 256, 0, stream>>>(hbf, wtcat3, xsd_bf, NN, 128, HC);
  gat_fused_pool4<<<(NN + 15) / 16, 256, 0, stream>>>(xsd_bf, xsd_bf + HIDC, pairs,
                                                      w_edge3, att3, b3, offs, batch, gp);

  // --- MLP head ---
  head_mlp<<<GG, 64, 0, stream>>>(gp, fc1_w, fc1_b, out_w, out_b, (float*)d_out);
}